// Round 4
// baseline (1092.963 us; speedup 1.0000x reference)
//
#include <hip/hip_runtime.h>

#define TT 4
#define BB 2
#define CC 128
#define DD 8
#define HHH 32
#define WWW 32
#define PP (DD*HHH*WWW)        // 8192
#define TSTRIDE (BB*CC*PP)     // 2097152
#define NWIN 8
#define SSS 1024
#define NHEAD 8
#define HDIM 16
#define THETA 0.7f
#define VTH 1.0f
#define NPERC (TT*BB*PP)       // 65536
#define EPSf 1e-5f

// padded x: [tb][c][dp(10)][hp(34)][32]; dp 0,9 and hp 0,33 are zero halos
#define XPAD_CSTRIDE (10*34*32)            // 10880
#define XPAD_TBSTRIDE (CC*XPAD_CSTRIDE)
#define XPAD_TOTAL ((size_t)TT*BB*XPAD_TBSTRIDE)   // 11,141,120

// ---------------- conv weight prep: fold CDC into center tap + transpose ----
// W2[og(8)][ic(128)][tap(27)][oo(16)]
__global__ __launch_bounds__(256) void prep_weights(const float* __restrict__ qw,
                                                    float* __restrict__ W2) {
    int oi = blockIdx.x*256 + threadIdx.x;
    if (oi >= CC*CC) return;
    int o  = oi >> 7;
    int ic = oi & 127;
    int og = o >> 4, oo = o & 15;
    const float* wp = qw + (size_t)oi*27;
    float kd = 0.f;
    #pragma unroll
    for (int t=0; t<9; t++) kd += wp[t] + wp[18+t];
    #pragma unroll
    for (int t=0; t<27; t++) {
        float v = wp[t] - ((t==13) ? THETA*kd : 0.f);
        W2[(((size_t)og*CC + ic)*27 + t)*16 + oo] = v;
    }
}

// ---------------- pointwise weight transpose: W[o][i] -> Wt[og][i][oo] ------
__global__ __launch_bounds__(256) void prep_cpw(const float* __restrict__ kw,
        const float* __restrict__ pw, float* __restrict__ Wk2,
        float* __restrict__ Wp2) {
    int i = blockIdx.x*256 + threadIdx.x;
    if (i >= CC*CC) return;
    int o = i >> 7, ic = i & 127;
    int dst = ((o>>4)*CC + ic)*16 + (o&15);
    Wk2[dst] = kw[i];
    Wp2[dst] = pw[i];
}

// ---------------- pad x with d and h halos ----------------------------------
__global__ __launch_bounds__(512) void pad_x(const float* __restrict__ x,
                                             float* __restrict__ xp) {
    int pos = blockIdx.x*512 + threadIdx.x;      // 0..10879 (+ guard)
    int tbc = blockIdx.y;                        // 0..1023
    if (pos >= XPAD_CSTRIDE) return;
    int dp  = pos / 1088;
    int rem = pos - dp*1088;
    int hp  = rem >> 5, w = rem & 31;
    float v = 0.f;
    if (dp >= 1 && dp <= 8 && hp >= 1 && hp <= 32)
        v = x[(size_t)tbc*PP + (size_t)(dp-1)*1024 + (hp-1)*32 + w];
    xp[(size_t)tbc*XPAD_CSTRIDE + pos] = v;
}

// ---------------- 3x3x3 conv (CDC folded): 4 w-positions x 16 oo per thread -
__global__ __launch_bounds__(256) void conv3d_v4(const float* __restrict__ xp,
                                                 const float* __restrict__ W2,
                                                 float* __restrict__ y) {
    int tid = threadIdx.x;          // 0..255
    int d   = blockIdx.x;           // 0..7
    int og  = blockIdx.y;
    int tb  = blockIdx.z;
    int h  = tid >> 3;              // 0..31
    int w0 = (tid & 7) * 4;

    float mwl = (w0 > 0)  ? 1.f : 0.f;
    float mwr = (w0 < 28) ? 1.f : 0.f;

    // base at (dp=d, hp=h) i.e. tap (dz=0, dhm=-1); row(dz,dh) = +(dz*34+dh)*32
    const float* xb = xp + (size_t)tb*XPAD_TBSTRIDE + ((size_t)d*34 + h)*32 + w0;
    const float* Wp = W2 + (size_t)og*CC*27*16;

    float acc[16][4];
    #pragma unroll
    for (int oo=0; oo<16; oo++)
        #pragma unroll
        for (int j=0; j<4; j++) acc[oo][j] = 0.f;

    #pragma unroll 1
    for (int ic=0; ic<CC; ic++) {
        const float* xc = xb + (size_t)ic*XPAD_CSTRIDE;
        const float* wr = Wp + ic*(27*16);
        #pragma unroll
        for (int dz=0; dz<3; dz++) {
            #pragma unroll
            for (int dh=0; dh<3; dh++) {
                const float* rp = xc + (dz*34 + dh)*32;
                float r[6];
                float4 f4 = *(const float4*)rp;
                r[0] = rp[-1] * mwl;
                r[1] = f4.x; r[2] = f4.y; r[3] = f4.z; r[4] = f4.w;
                r[5] = rp[4] * mwr;
                #pragma unroll
                for (int dw=0; dw<3; dw++) {
                    const float* wv = wr + ((dz*3+dh)*3 + dw)*16;  // uniform -> s_load
                    #pragma unroll
                    for (int j=0; j<4; j++) {
                        float xv = r[j+dw];
                        #pragma unroll
                        for (int oo=0; oo<16; oo++)
                            acc[oo][j] += wv[oo]*xv;
                    }
                }
            }
        }
    }
    #pragma unroll
    for (int oo=0; oo<16; oo++) {
        float4 o4;
        o4.x=acc[oo][0]; o4.y=acc[oo][1]; o4.z=acc[oo][2]; o4.w=acc[oo][3];
        *(float4*)&y[((size_t)tb*CC + og*16+oo)*PP + d*1024 + h*32 + w0] = o4;
    }
}

// ---------------- pointwise GEMM: float4 x, SGPR weights --------------------
__global__ __launch_bounds__(256) void gemm_cp4(const float* __restrict__ xin,
                                                const float* __restrict__ Wt,
                                                float* __restrict__ y) {
    int tid  = threadIdx.x;
    int tile = blockIdx.x, og = blockIdx.y, tb = blockIdx.z;
    const float* xb = xin + (size_t)tb*CC*PP + tile*1024 + tid*4;
    const float* wp = Wt + (size_t)og*CC*16;
    float acc[16][4];
    #pragma unroll
    for (int oo=0;oo<16;oo++)
        #pragma unroll
        for (int j=0;j<4;j++) acc[oo][j]=0.f;
    #pragma unroll 2
    for (int i=0;i<CC;i++){
        float4 xv = *(const float4*)(xb + (size_t)i*PP);
        const float* wv = wp + i*16;               // uniform -> s_load_dwordx16
        #pragma unroll
        for (int oo=0;oo<16;oo++){
            acc[oo][0] += wv[oo]*xv.x;
            acc[oo][1] += wv[oo]*xv.y;
            acc[oo][2] += wv[oo]*xv.z;
            acc[oo][3] += wv[oo]*xv.w;
        }
    }
    #pragma unroll
    for (int oo=0;oo<16;oo++){
        float4 o4;
        o4.x=acc[oo][0]; o4.y=acc[oo][1]; o4.z=acc[oo][2]; o4.w=acc[oo][3];
        *(float4*)&y[((size_t)tb*CC + og*16+oo)*PP + tile*1024 + tid*4] = o4;
    }
}

// ---------------- per-(src,b,win,c) sum & sumsq partials ---------------------
__global__ __launch_bounds__(128) void win_stats(const float* __restrict__ q,
        const float* __restrict__ k, const float* __restrict__ x,
        float* __restrict__ rsum, float* __restrict__ rsq) {
    int blk = blockIdx.x;
    int src = blk >> 11;
    int r   = blk & 2047;
    const float* base = (src==0) ? q : ((src==1) ? k : x);
    int c  = r & 127;
    int wi = (r >> 7) & 7;
    int b  = r >> 10;
    int wd = wi>>2, wh = (wi>>1)&1, ww = wi&1;
    int tid = threadIdx.x;
    float s=0.f, s2=0.f;
    for (int t=0;t<TT;t++){
        const float* p = base + ((size_t)(t*BB+b)*CC + c)*PP;
        for (int si=tid; si<SSS; si+=128){
            int ld = si>>8, lh=(si>>4)&15, lw=si&15;
            float v = p[((wd*4+ld)<<10) + ((wh*16+lh)<<5) + (ww*16+lw)];
            s += v; s2 += v*v;
        }
    }
    __shared__ float ls[128], ls2[128];
    ls[tid]=s; ls2[tid]=s2; __syncthreads();
    for (int off=64;off>0;off>>=1){
        if(tid<off){ ls[tid]+=ls[tid+off]; ls2[tid]+=ls2[tid+off]; }
        __syncthreads();
    }
    if (tid==0){ rsum[blk]=ls[0]; rsq[blk]=ls2[0]; }
}

// ---------------- finalize per-channel stats for q,k,v ----------------------
__global__ __launch_bounds__(384) void stats_fin(const float* __restrict__ rsum,
        const float* __restrict__ rsq, float* __restrict__ sums) {
    int tid = threadIdx.x;
    int src = tid >> 7, c = tid & 127;
    float s=0.f, s2=0.f;
    for (int bw=0; bw<16; bw++){
        int idx = src*2048 + bw*128 + c;
        s  += rsum[idx];
        s2 += rsq[idx];
    }
    sums[src*256 + c]       = s;
    sums[src*256 + 128 + c] = s2;
}

// ---------------- routing: normalize regions, a_r, top-4 --------------------
__global__ __launch_bounds__(128) void route_topk(const float* __restrict__ qreg,
        const float* __restrict__ kreg,
        const float* __restrict__ qsum, const float* __restrict__ qsq,
        const float* __restrict__ ksum, const float* __restrict__ ksq,
        const float* __restrict__ qg, const float* __restrict__ qb,
        const float* __restrict__ kg, const float* __restrict__ kb,
        int* __restrict__ idxout) {
    __shared__ float qn[16*128], kn[16*128], ar[16*8];
    int tid = threadIdx.x;
    for (int e=tid; e<16*128; e+=128){
        int c = e&127;
        float qm = qsum[c]*(1.f/NPERC);
        float qv = qsq[c]*(1.f/NPERC) - qm*qm;
        float qr = rsqrtf(qv + EPSf);
        qn[e] = (qreg[e]*(1.f/(TT*SSS)) - qm)*qr*qg[c] + qb[c];
        float km = ksum[c]*(1.f/NPERC);
        float kv = ksq[c]*(1.f/NPERC) - km*km;
        float kr = rsqrtf(kv + EPSf);
        kn[e] = (kreg[e]*(1.f/(TT*SSS)) - km)*kr*kg[c] + kb[c];
    }
    __syncthreads();
    {
        int b = tid>>6, w=(tid>>3)&7, v=tid&7;
        float s=0.f;
        for (int c=0;c<128;c++) s += qn[(b*8+w)*128+c]*kn[(b*8+v)*128+c];
        ar[(b*8+w)*8+v] = s * 0.25f;
    }
    __syncthreads();
    if (tid < 16){
        const float* row = &ar[tid*8];
        bool used[8] = {false,false,false,false,false,false,false,false};
        for (int j=0;j<4;j++){
            int best=0; float bv=-3.0e38f;
            for (int v=0; v<8; v++){
                if (!used[v] && row[v] > bv){ bv=row[v]; best=v; }
            }
            used[best]=true;
            idxout[tid*4+j]=best;
        }
    }
}

// ---------------- LIF with fused BN, spikes in c-major windowed layout ------
__global__ __launch_bounds__(256) void lif_bn_win(const float* __restrict__ xin,
        float* __restrict__ spk,
        const float* __restrict__ sum, const float* __restrict__ sq,
        const float* __restrict__ gamma, const float* __restrict__ beta) {
    int e = blockIdx.x*256 + threadIdx.x;
    if (e >= BB*CC*PP) return;
    int p = e & (PP-1);
    int c = (e >> 13) & 127;
    int b = e >> 20;
    float mean = sum[c]*(1.f/NPERC);
    float var  = sq[c]*(1.f/NPERC) - mean*mean;
    float sc = rsqrtf(var+EPSf)*gamma[c];
    float sh = beta[c] - mean*sc;
    int d = p>>10, h=(p>>5)&31, w=p&31;
    int wi = ((d>>2)*2 + (h>>4))*2 + (w>>4);
    int si = (((d&3)<<4) + (h&15))*16 + (w&15);
    size_t widx = ((size_t)(b*NWIN+wi)*CC + c)*SSS + si;
    float v=0.f;
    #pragma unroll
    for (int t=0;t<TT;t++){
        float xn = xin[(size_t)t*TSTRIDE + e]*sc + sh;
        v = (v+xn)*0.5f;
        float s = (v>=VTH)?1.f:0.f;
        spk[(size_t)t*TSTRIDE + widx] = s;
        v *= (1.f - s);
    }
}

// ---------------- window attention + fused output LIF -> standard layout ----
__global__ __launch_bounds__(256) void attn_lif(const float* __restrict__ qspk,
        const float* __restrict__ kspk, const float* __restrict__ vspk,
        const int* __restrict__ idx, float* __restrict__ out2) {
    int id = blockIdx.x*256 + threadIdx.x;   // B*W*H*S = 131072
    if (id >= BB*NWIN*NHEAD*SSS) return;
    int s  = id & 1023;
    int hh = (id>>10) & 7;
    int wi = (id>>13) & 7;
    int b  = id>>16;
    int bw = b*NWIN+wi;
    size_t qbase = ((size_t)bw*CC + hh*HDIM)*SSS + s;
    size_t sbase[4];
    #pragma unroll
    for (int j=0;j<4;j++){
        int src = idx[bw*4+j];
        sbase[j] = ((size_t)(b*NWIN+src)*CC + hh*HDIM)*SSS + s;
    }
    // standard-layout output position for (wi, si=s)
    int wd = wi>>2, wh = (wi>>1)&1, ww = wi&1;
    int d3 = wd*4 + (s>>8), h3 = wh*16 + ((s>>4)&15), w3 = ww*16 + (s&15);
    int p  = (d3<<10) + (h3<<5) + w3;
    size_t obase = ((size_t)b*CC + hh*HDIM)*PP + p;

    float v=0.f;
    float v2[16];
    #pragma unroll
    for (int dd=0; dd<16; dd++) v2[dd]=0.f;

    #pragma unroll 1
    for (int t=0;t<TT;t++){
        size_t toff = (size_t)t*TSTRIDE;
        float km[16], vm[16];
        #pragma unroll
        for (int dd=0;dd<16;dd++){ km[dd]=0.f; vm[dd]=0.f; }
        #pragma unroll
        for (int j=0;j<4;j++){
            const float* kp = kspk+toff+sbase[j];
            const float* vp = vspk+toff+sbase[j];
            #pragma unroll
            for (int dd=0; dd<16; dd++){
                km[dd] += kp[(size_t)dd*SSS];
                vm[dd] += vp[(size_t)dd*SSS];
            }
        }
        const float* qp = qspk+toff+qbase;
        float att=0.f;
        #pragma unroll
        for (int dd=0;dd<16;dd++) att += qp[(size_t)dd*SSS]*km[dd];
        att *= 0.25f;
        v = (v+att)*0.5f;
        float sp = (v>=VTH)?1.f:0.f;
        v *= (1.f-sp);
        float spq = sp*0.25f;
        float* op = out2 + toff + obase;
        #pragma unroll
        for (int dd=0;dd<16;dd++){
            float ov = spq*vm[dd];
            v2[dd] = (v2[dd]+ov)*0.5f;
            float s2 = (v2[dd]>=VTH)?1.f:0.f;
            v2[dd] *= (1.f-s2);
            op[(size_t)dd*PP] = s2;
        }
    }
}

// ---------------- p-stats: partials over (tb,c), then finalize ---------------
__global__ __launch_bounds__(256) void pstats_part(const float* __restrict__ xin,
        float* __restrict__ part_sum, float* __restrict__ part_sq) {
    int blk = blockIdx.x;                    // tb*128 + c
    int c = blk & 127, tb = blk >> 7;
    int tid = threadIdx.x;
    const float* p = xin + ((size_t)tb*CC + c)*PP;
    float s=0.f, s2=0.f;
    for (int i=tid; i<PP; i+=256){ float v=p[i]; s+=v; s2+=v*v; }
    __shared__ float ls[256], ls2[256];
    ls[tid]=s; ls2[tid]=s2; __syncthreads();
    for (int off=128; off>0; off>>=1){
        if (tid<off){ ls[tid]+=ls[tid+off]; ls2[tid]+=ls2[tid+off]; }
        __syncthreads();
    }
    if (tid==0){ part_sum[blk]=ls[0]; part_sq[blk]=ls2[0]; }
}

__global__ __launch_bounds__(128) void pstats_fin(const float* __restrict__ part_sum,
        const float* __restrict__ part_sq, float* __restrict__ sum,
        float* __restrict__ sq) {
    int c = threadIdx.x;
    float s=0.f, s2=0.f;
    for (int tb=0; tb<8; tb++){
        s  += part_sum[tb*128+c];
        s2 += part_sq[tb*128+c];
    }
    sum[c]=s; sq[c]=s2;
}

// ---------------- final BN apply ---------------------------------------------
__global__ __launch_bounds__(256) void bn_apply(const float* __restrict__ xin,
        float* __restrict__ yout,
        const float* __restrict__ sum, const float* __restrict__ sq,
        const float* __restrict__ gamma, const float* __restrict__ beta) {
    size_t i = (size_t)blockIdx.x*256 + threadIdx.x;
    if (i >= (size_t)TT*BB*CC*PP) return;
    int c = (int)((i>>13)&127);
    float mean = sum[c]*(1.f/NPERC);
    float var  = sq[c]*(1.f/NPERC) - mean*mean;
    float sc = rsqrtf(var+EPSf)*gamma[c];
    float sh = beta[c] - mean*sc;
    yout[i] = xin[i]*sc + sh;
}

extern "C" void kernel_launch(void* const* d_in, const int* in_sizes, int n_in,
                              void* d_out, int out_size, void* d_ws, size_t ws_size,
                              hipStream_t stream) {
    const float* x  = (const float*)d_in[0];
    const float* qw = (const float*)d_in[1];
    const float* qg = (const float*)d_in[2];
    const float* qb = (const float*)d_in[3];
    const float* kw = (const float*)d_in[4];
    const float* kg = (const float*)d_in[5];
    const float* kb = (const float*)d_in[6];
    const float* vg = (const float*)d_in[7];
    const float* vb = (const float*)d_in[8];
    const float* pw = (const float*)d_in[9];
    const float* pg = (const float*)d_in[10];
    const float* pb = (const float*)d_in[11];
    float* out = (float*)d_out;
    float* ws  = (float*)d_ws;

    const size_t NEL = (size_t)TT*TSTRIDE;   // 8388608
    float* qconv = ws;
    float* kconv = ws + NEL;
    float* qspk  = ws + 2*NEL;
    float* kspk  = ws + 3*NEL;
    float* vspk  = ws + 4*NEL;
    float* wmod  = ws + 5*NEL;               // 442368 floats
    float* stats = ws + 5*NEL + 442368;
    float *qsum=stats,     *qsq=stats+128,  *ksum=stats+256, *ksq=stats+384,
          *vsum=stats+512, *vsq=stats+640,  *psum=stats+768, *psq=stats+896;
    float* rsum = stats + 1024;              // 6144
    float* rsq  = rsum + 6144;               // 6144
    float* ppart_sum = rsq + 6144;           // 1024
    float* ppart_sq  = ppart_sum + 1024;     // 1024
    int*   idxp = (int*)(ppart_sq + 1024);   // 64 ints
    float* Wk2 = stats + 16384;              // 16384
    float* Wp2 = Wk2 + 16384;                // 16384

    // lifetimes: xpad occupies qspk..(+11.14M, spills into kspk) until conv done
    float* xpad  = qspk;
    float* out2  = kconv;                    // kconv dead after lif_bn_win(k)
    float* pconv = qspk;                     // qspk dead after attn

    prep_weights<<<64,256,0,stream>>>(qw, wmod);
    prep_cpw<<<64,256,0,stream>>>(kw, pw, Wk2, Wp2);
    {
        dim3 pg2((XPAD_CSTRIDE+511)/512, TT*BB*CC);
        pad_x<<<pg2,512,0,stream>>>(x, xpad);
    }
    {
        dim3 cvg(8,8,8);
        conv3d_v4<<<cvg,256,0,stream>>>(xpad, wmod, qconv);
        gemm_cp4<<<cvg,256,0,stream>>>(x, Wk2, kconv);
    }
    win_stats<<<6144,128,0,stream>>>(qconv, kconv, x, rsum, rsq);
    stats_fin<<<1,384,0,stream>>>(rsum, rsq, stats);
    route_topk<<<1,128,0,stream>>>(rsum, rsum+2048, qsum,qsq,ksum,ksq,qg,qb,kg,kb,idxp);
    lif_bn_win<<<8192,256,0,stream>>>(qconv, qspk, qsum,qsq, qg,qb);
    lif_bn_win<<<8192,256,0,stream>>>(kconv, kspk, ksum,ksq, kg,kb);
    lif_bn_win<<<8192,256,0,stream>>>(x,     vspk, vsum,vsq, vg,vb);
    attn_lif<<<512,256,0,stream>>>(qspk,kspk,vspk,idxp,out2);
    {
        dim3 cvg(8,8,8);
        gemm_cp4<<<cvg,256,0,stream>>>(out2, Wp2, pconv);
    }
    pstats_part<<<1024,256,0,stream>>>(pconv, ppart_sum, ppart_sq);
    pstats_fin<<<1,128,0,stream>>>(ppart_sum, ppart_sq, psum, psq);
    bn_apply<<<32768,256,0,stream>>>(pconv, out, psum, psq, pg, pb);
}

// Round 5
// 1016.122 us; speedup vs baseline: 1.0756x; 1.0756x over previous
//
#include <hip/hip_runtime.h>

#define TT 4
#define BB 2
#define CC 128
#define DD 8
#define HHH 32
#define WWW 32
#define PP (DD*HHH*WWW)        // 8192
#define TSTRIDE (BB*CC*PP)     // 2097152
#define NWIN 8
#define SSS 1024
#define NHEAD 8
#define HDIM 16
#define THETA 0.7f
#define VTH 1.0f
#define NPERC (TT*BB*PP)       // 65536
#define EPSf 1e-5f

// padded x: [tb][c][dp(10)][hp(34)][32]; dp 0,9 and hp 0,33 are zero halos
#define XPAD_CSTRIDE (10*34*32)            // 10880
#define XPAD_TBSTRIDE (CC*XPAD_CSTRIDE)
#define XPAD_TOTAL ((size_t)TT*BB*XPAD_TBSTRIDE)   // 11,141,120

// ---------------- conv weight prep: fold CDC into center tap + transpose ----
// W3[og(16)][ic(128)][tap(27)][oo(8)]
__global__ __launch_bounds__(256) void prep_weights(const float* __restrict__ qw,
                                                    float* __restrict__ W3) {
    int oi = blockIdx.x*256 + threadIdx.x;
    if (oi >= CC*CC) return;
    int o  = oi >> 7;
    int ic = oi & 127;
    int og = o >> 3, oo = o & 7;
    const float* wp = qw + (size_t)oi*27;
    float kd = 0.f;
    #pragma unroll
    for (int t=0; t<9; t++) kd += wp[t] + wp[18+t];
    #pragma unroll
    for (int t=0; t<27; t++) {
        float v = wp[t] - ((t==13) ? THETA*kd : 0.f);
        W3[(((size_t)og*CC + ic)*27 + t)*8 + oo] = v;
    }
}

// ---------------- pointwise weight transpose: W[o][i] -> Wt[og][i][oo16] ----
__global__ __launch_bounds__(256) void prep_cpw(const float* __restrict__ kw,
        const float* __restrict__ pw, float* __restrict__ Wk2,
        float* __restrict__ Wp2) {
    int i = blockIdx.x*256 + threadIdx.x;
    if (i >= CC*CC) return;
    int o = i >> 7, ic = i & 127;
    int dst = ((o>>4)*CC + ic)*16 + (o&15);
    Wk2[dst] = kw[i];
    Wp2[dst] = pw[i];
}

// ---------------- pad x with d and h halos ----------------------------------
__global__ __launch_bounds__(512) void pad_x(const float* __restrict__ x,
                                             float* __restrict__ xp) {
    int pos = blockIdx.x*512 + threadIdx.x;      // 0..10879
    int tbc = blockIdx.y;                        // 0..1023
    if (pos >= XPAD_CSTRIDE) return;
    int dp  = pos / 1088;
    int rem = pos - dp*1088;
    int hp  = rem >> 5, w = rem & 31;
    float v = 0.f;
    if (dp >= 1 && dp <= 8 && hp >= 1 && hp <= 32)
        v = x[(size_t)tbc*PP + (size_t)(dp-1)*1024 + (hp-1)*32 + w];
    xp[(size_t)tbc*XPAD_CSTRIDE + pos] = v;
}

// ---------------- 3x3x3 conv (CDC folded): 2 w-positions x 8 oo per thread --
// 8192 waves total (32/CU); acc[8][2]=16 VGPRs -> no AGPR bounce.
__global__ __launch_bounds__(256) void conv3d_p2(const float* __restrict__ xp,
                                                 const float* __restrict__ W3,
                                                 float* __restrict__ y) {
    int tid = threadIdx.x;          // 0..255
    int bx  = blockIdx.x;           // 0..15: d = bx>>1, hbase = (bx&1)*16
    int og  = blockIdx.y;           // 0..15 (8 oo each)
    int tb  = blockIdx.z;
    int d  = bx >> 1;
    int h  = ((bx & 1) << 4) + (tid >> 4);     // 0..31
    int w0 = (tid & 15) * 2;                   // 0,2,..30

    float mwl = (w0 > 0)  ? 1.f : 0.f;
    float mwr = (w0 < 30) ? 1.f : 0.f;

    const float* xb = xp + (size_t)tb*XPAD_TBSTRIDE + ((size_t)d*34 + h)*32 + w0;
    const float* Wp = W3 + (size_t)og*CC*27*8;

    float acc[8][2];
    #pragma unroll
    for (int oo=0; oo<8; oo++){ acc[oo][0]=0.f; acc[oo][1]=0.f; }

    #pragma unroll 1
    for (int ic=0; ic<CC; ic++) {
        const float* xc = xb + (size_t)ic*XPAD_CSTRIDE;
        const float* wr = Wp + ic*(27*8);
        #pragma unroll
        for (int dz=0; dz<3; dz++) {
            #pragma unroll
            for (int dh=0; dh<3; dh++) {
                const float* rp = xc + (dz*34 + dh)*32;
                float2 f2 = *(const float2*)rp;
                float r[4];
                r[0] = rp[-1] * mwl;
                r[1] = f2.x; r[2] = f2.y;
                r[3] = rp[2] * mwr;
                #pragma unroll
                for (int dw=0; dw<3; dw++) {
                    const float* wv = wr + ((dz*3+dh)*3 + dw)*8;  // uniform -> s_load_dwordx8
                    #pragma unroll
                    for (int oo=0; oo<8; oo++) {
                        acc[oo][0] += wv[oo]*r[dw];
                        acc[oo][1] += wv[oo]*r[dw+1];
                    }
                }
            }
        }
    }
    #pragma unroll
    for (int oo=0; oo<8; oo++) {
        float2 o2; o2.x = acc[oo][0]; o2.y = acc[oo][1];
        *(float2*)&y[((size_t)tb*CC + og*8+oo)*PP + d*1024 + h*32 + w0] = o2;
    }
}

// ---------------- pointwise GEMM: float4 x, SGPR weights --------------------
__global__ __launch_bounds__(256) void gemm_cp4(const float* __restrict__ xin,
                                                const float* __restrict__ Wt,
                                                float* __restrict__ y) {
    int tid  = threadIdx.x;
    int tile = blockIdx.x, og = blockIdx.y, tb = blockIdx.z;
    const float* xb = xin + (size_t)tb*CC*PP + tile*1024 + tid*4;
    const float* wp = Wt + (size_t)og*CC*16;
    float acc[16][4];
    #pragma unroll
    for (int oo=0;oo<16;oo++)
        #pragma unroll
        for (int j=0;j<4;j++) acc[oo][j]=0.f;
    #pragma unroll 2
    for (int i=0;i<CC;i++){
        float4 xv = *(const float4*)(xb + (size_t)i*PP);
        const float* wv = wp + i*16;               // uniform -> s_load_dwordx16
        #pragma unroll
        for (int oo=0;oo<16;oo++){
            acc[oo][0] += wv[oo]*xv.x;
            acc[oo][1] += wv[oo]*xv.y;
            acc[oo][2] += wv[oo]*xv.z;
            acc[oo][3] += wv[oo]*xv.w;
        }
    }
    #pragma unroll
    for (int oo=0;oo<16;oo++){
        float4 o4;
        o4.x=acc[oo][0]; o4.y=acc[oo][1]; o4.z=acc[oo][2]; o4.w=acc[oo][3];
        *(float4*)&y[((size_t)tb*CC + og*16+oo)*PP + tile*1024 + tid*4] = o4;
    }
}

// ---------------- per-(src,b,win,c) sum & sumsq partials ---------------------
__global__ __launch_bounds__(128) void win_stats(const float* __restrict__ q,
        const float* __restrict__ k, const float* __restrict__ x,
        float* __restrict__ rsum, float* __restrict__ rsq) {
    int blk = blockIdx.x;
    int src = blk >> 11;
    int r   = blk & 2047;
    const float* base = (src==0) ? q : ((src==1) ? k : x);
    int c  = r & 127;
    int wi = (r >> 7) & 7;
    int b  = r >> 10;
    int wd = wi>>2, wh = (wi>>1)&1, ww = wi&1;
    int tid = threadIdx.x;
    float s=0.f, s2=0.f;
    for (int t=0;t<TT;t++){
        const float* p = base + ((size_t)(t*BB+b)*CC + c)*PP;
        for (int si=tid; si<SSS; si+=128){
            int ld = si>>8, lh=(si>>4)&15, lw=si&15;
            float v = p[((wd*4+ld)<<10) + ((wh*16+lh)<<5) + (ww*16+lw)];
            s += v; s2 += v*v;
        }
    }
    __shared__ float ls[128], ls2[128];
    ls[tid]=s; ls2[tid]=s2; __syncthreads();
    for (int off=64;off>0;off>>=1){
        if(tid<off){ ls[tid]+=ls[tid+off]; ls2[tid]+=ls2[tid+off]; }
        __syncthreads();
    }
    if (tid==0){ rsum[blk]=ls[0]; rsq[blk]=ls2[0]; }
}

// ---------------- finalize per-channel stats for q,k,v ----------------------
__global__ __launch_bounds__(384) void stats_fin(const float* __restrict__ rsum,
        const float* __restrict__ rsq, float* __restrict__ sums) {
    int tid = threadIdx.x;
    int src = tid >> 7, c = tid & 127;
    float s=0.f, s2=0.f;
    for (int bw=0; bw<16; bw++){
        int idx = src*2048 + bw*128 + c;
        s  += rsum[idx];
        s2 += rsq[idx];
    }
    sums[src*256 + c]       = s;
    sums[src*256 + 128 + c] = s2;
}

// ---------------- routing: normalize regions, a_r, top-4 --------------------
__global__ __launch_bounds__(128) void route_topk(const float* __restrict__ qreg,
        const float* __restrict__ kreg,
        const float* __restrict__ qsum, const float* __restrict__ qsq,
        const float* __restrict__ ksum, const float* __restrict__ ksq,
        const float* __restrict__ qg, const float* __restrict__ qb,
        const float* __restrict__ kg, const float* __restrict__ kb,
        int* __restrict__ idxout) {
    __shared__ float qn[16*128], kn[16*128], ar[16*8];
    int tid = threadIdx.x;
    for (int e=tid; e<16*128; e+=128){
        int c = e&127;
        float qm = qsum[c]*(1.f/NPERC);
        float qv = qsq[c]*(1.f/NPERC) - qm*qm;
        float qr = rsqrtf(qv + EPSf);
        qn[e] = (qreg[e]*(1.f/(TT*SSS)) - qm)*qr*qg[c] + qb[c];
        float km = ksum[c]*(1.f/NPERC);
        float kv = ksq[c]*(1.f/NPERC) - km*km;
        float kr = rsqrtf(kv + EPSf);
        kn[e] = (kreg[e]*(1.f/(TT*SSS)) - km)*kr*kg[c] + kb[c];
    }
    __syncthreads();
    {
        int b = tid>>6, w=(tid>>3)&7, v=tid&7;
        float s=0.f;
        for (int c=0;c<128;c++) s += qn[(b*8+w)*128+c]*kn[(b*8+v)*128+c];
        ar[(b*8+w)*8+v] = s * 0.25f;
    }
    __syncthreads();
    if (tid < 16){
        const float* row = &ar[tid*8];
        bool used[8] = {false,false,false,false,false,false,false,false};
        for (int j=0;j<4;j++){
            int best=0; float bv=-3.0e38f;
            for (int v=0; v<8; v++){
                if (!used[v] && row[v] > bv){ bv=row[v]; best=v; }
            }
            used[best]=true;
            idxout[tid*4+j]=best;
        }
    }
}

// ---------------- LIF+BN for q,k,v in ONE launch (grid.y = src) -------------
// spikes to c-major windowed layout: widx = ((bw*CC + c)*SSS + si)
__global__ __launch_bounds__(256) void lif_bn_win3(const float* __restrict__ qin,
        const float* __restrict__ kin, const float* __restrict__ xin,
        float* __restrict__ qs, float* __restrict__ ks, float* __restrict__ vs,
        const float* __restrict__ stats,
        const float* __restrict__ qg, const float* __restrict__ qb,
        const float* __restrict__ kg, const float* __restrict__ kb,
        const float* __restrict__ vg, const float* __restrict__ vb) {
    int src = blockIdx.y;
    const float* in  = (src==0) ? qin : ((src==1) ? kin : xin);
    float*       spk = (src==0) ? qs  : ((src==1) ? ks  : vs);
    const float* gamma = (src==0) ? qg : ((src==1) ? kg : vg);
    const float* beta  = (src==0) ? qb : ((src==1) ? kb : vb);
    int e = blockIdx.x*256 + threadIdx.x;
    if (e >= BB*CC*PP) return;
    int p = e & (PP-1);
    int c = (e >> 13) & 127;
    int b = e >> 20;
    float mean = stats[src*256 + c]*(1.f/NPERC);
    float var  = stats[src*256 + 128 + c]*(1.f/NPERC) - mean*mean;
    float sc = rsqrtf(var+EPSf)*gamma[c];
    float sh = beta[c] - mean*sc;
    int d = p>>10, h=(p>>5)&31, w=p&31;
    int wi = ((d>>2)*2 + (h>>4))*2 + (w>>4);
    int si = (((d&3)<<4) + (h&15))*16 + (w&15);
    size_t widx = ((size_t)(b*NWIN+wi)*CC + c)*SSS + si;
    float v=0.f;
    #pragma unroll
    for (int t=0;t<TT;t++){
        float xn = in[(size_t)t*TSTRIDE + e]*sc + sh;
        v = (v+xn)*0.5f;
        float s = (v>=VTH)?1.f:0.f;
        spk[(size_t)t*TSTRIDE + widx] = s;
        v *= (1.f - s);
    }
}

// ---------------- window attention + fused output LIF -> standard layout ----
__global__ __launch_bounds__(256) void attn_lif(const float* __restrict__ qspk,
        const float* __restrict__ kspk, const float* __restrict__ vspk,
        const int* __restrict__ idx, float* __restrict__ out2) {
    int id = blockIdx.x*256 + threadIdx.x;   // B*W*H*S = 131072
    if (id >= BB*NWIN*NHEAD*SSS) return;
    int s  = id & 1023;
    int hh = (id>>10) & 7;
    int wi = (id>>13) & 7;
    int b  = id>>16;
    int bw = b*NWIN+wi;
    size_t qbase = ((size_t)bw*CC + hh*HDIM)*SSS + s;
    size_t sbase[4];
    #pragma unroll
    for (int j=0;j<4;j++){
        int src = idx[bw*4+j];
        sbase[j] = ((size_t)(b*NWIN+src)*CC + hh*HDIM)*SSS + s;
    }
    int wd = wi>>2, wh = (wi>>1)&1, ww = wi&1;
    int d3 = wd*4 + (s>>8), h3 = wh*16 + ((s>>4)&15), w3 = ww*16 + (s&15);
    int p  = (d3<<10) + (h3<<5) + w3;
    size_t obase = ((size_t)b*CC + hh*HDIM)*PP + p;

    float v=0.f;
    float v2[16];
    #pragma unroll
    for (int dd=0; dd<16; dd++) v2[dd]=0.f;

    #pragma unroll 1
    for (int t=0;t<TT;t++){
        size_t toff = (size_t)t*TSTRIDE;
        float km[16], vm[16];
        #pragma unroll
        for (int dd=0;dd<16;dd++){ km[dd]=0.f; vm[dd]=0.f; }
        #pragma unroll
        for (int j=0;j<4;j++){
            const float* kp = kspk+toff+sbase[j];
            const float* vp = vspk+toff+sbase[j];
            #pragma unroll
            for (int dd=0; dd<16; dd++){
                km[dd] += kp[(size_t)dd*SSS];
                vm[dd] += vp[(size_t)dd*SSS];
            }
        }
        const float* qp = qspk+toff+qbase;
        float att=0.f;
        #pragma unroll
        for (int dd=0;dd<16;dd++) att += qp[(size_t)dd*SSS]*km[dd];
        att *= 0.25f;
        v = (v+att)*0.5f;
        float sp = (v>=VTH)?1.f:0.f;
        v *= (1.f-sp);
        float spq = sp*0.25f;
        float* op = out2 + toff + obase;
        #pragma unroll
        for (int dd=0;dd<16;dd++){
            float ov = spq*vm[dd];
            v2[dd] = (v2[dd]+ov)*0.5f;
            float s2 = (v2[dd]>=VTH)?1.f:0.f;
            v2[dd] *= (1.f-s2);
            op[(size_t)dd*PP] = s2;
        }
    }
}

// ---------------- p-stats: partials over (tb,c), then finalize ---------------
__global__ __launch_bounds__(256) void pstats_part(const float* __restrict__ xin,
        float* __restrict__ part_sum, float* __restrict__ part_sq) {
    int blk = blockIdx.x;                    // tb*128 + c
    int c = blk & 127, tb = blk >> 7;
    int tid = threadIdx.x;
    const float* p = xin + ((size_t)tb*CC + c)*PP;
    float s=0.f, s2=0.f;
    for (int i=tid; i<PP; i+=256){ float v=p[i]; s+=v; s2+=v*v; }
    __shared__ float ls[256], ls2[256];
    ls[tid]=s; ls2[tid]=s2; __syncthreads();
    for (int off=128; off>0; off>>=1){
        if (tid<off){ ls[tid]+=ls[tid+off]; ls2[tid]+=ls2[tid+off]; }
        __syncthreads();
    }
    if (tid==0){ part_sum[blk]=ls[0]; part_sq[blk]=ls2[0]; }
}

__global__ __launch_bounds__(128) void pstats_fin(const float* __restrict__ part_sum,
        const float* __restrict__ part_sq, float* __restrict__ sum,
        float* __restrict__ sq) {
    int c = threadIdx.x;
    float s=0.f, s2=0.f;
    for (int tb=0; tb<8; tb++){
        s  += part_sum[tb*128+c];
        s2 += part_sq[tb*128+c];
    }
    sum[c]=s; sq[c]=s2;
}

// ---------------- final BN apply ---------------------------------------------
__global__ __launch_bounds__(256) void bn_apply(const float* __restrict__ xin,
        float* __restrict__ yout,
        const float* __restrict__ sum, const float* __restrict__ sq,
        const float* __restrict__ gamma, const float* __restrict__ beta) {
    size_t i = (size_t)blockIdx.x*256 + threadIdx.x;
    if (i >= (size_t)TT*BB*CC*PP) return;
    int c = (int)((i>>13)&127);
    float mean = sum[c]*(1.f/NPERC);
    float var  = sq[c]*(1.f/NPERC) - mean*mean;
    float sc = rsqrtf(var+EPSf)*gamma[c];
    float sh = beta[c] - mean*sc;
    yout[i] = xin[i]*sc + sh;
}

extern "C" void kernel_launch(void* const* d_in, const int* in_sizes, int n_in,
                              void* d_out, int out_size, void* d_ws, size_t ws_size,
                              hipStream_t stream) {
    const float* x  = (const float*)d_in[0];
    const float* qw = (const float*)d_in[1];
    const float* qg = (const float*)d_in[2];
    const float* qb = (const float*)d_in[3];
    const float* kw = (const float*)d_in[4];
    const float* kg = (const float*)d_in[5];
    const float* kb = (const float*)d_in[6];
    const float* vg = (const float*)d_in[7];
    const float* vb = (const float*)d_in[8];
    const float* pw = (const float*)d_in[9];
    const float* pg = (const float*)d_in[10];
    const float* pb = (const float*)d_in[11];
    float* out = (float*)d_out;
    float* ws  = (float*)d_ws;

    const size_t NEL = (size_t)TT*TSTRIDE;   // 8388608
    float* qconv = ws;
    float* kconv = ws + NEL;
    float* qspk  = ws + 2*NEL;
    float* kspk  = ws + 3*NEL;
    float* vspk  = ws + 4*NEL;
    float* wmod  = ws + 5*NEL;               // 442368 floats
    float* stats = ws + 5*NEL + 442368;
    float *qsum=stats,     *qsq=stats+128,  *ksum=stats+256, *ksq=stats+384,
          *psum=stats+768, *psq=stats+896;
    float* rsum = stats + 1024;              // 6144
    float* rsq  = rsum + 6144;               // 6144
    float* ppart_sum = rsq + 6144;           // 1024
    float* ppart_sq  = ppart_sum + 1024;     // 1024
    int*   idxp = (int*)(ppart_sq + 1024);   // 64 ints
    float* Wk2 = stats + 16384;              // 16384
    float* Wp2 = Wk2 + 16384;                // 16384

    // lifetimes: xpad occupies qspk..(+11.14M, spills into kspk) until conv done
    float* xpad  = qspk;
    float* out2  = kconv;                    // kconv dead after lif(k)
    float* pconv = qspk;                     // qspk dead after attn

    prep_weights<<<64,256,0,stream>>>(qw, wmod);
    prep_cpw<<<64,256,0,stream>>>(kw, pw, Wk2, Wp2);
    {
        dim3 pg2((XPAD_CSTRIDE+511)/512, TT*BB*CC);
        pad_x<<<pg2,512,0,stream>>>(x, xpad);
    }
    {
        dim3 cvg(16,16,8);
        conv3d_p2<<<cvg,256,0,stream>>>(xpad, wmod, qconv);
        dim3 gg(8,8,8);
        gemm_cp4<<<gg,256,0,stream>>>(x, Wk2, kconv);
    }
    win_stats<<<6144,128,0,stream>>>(qconv, kconv, x, rsum, rsq);
    stats_fin<<<1,384,0,stream>>>(rsum, rsq, stats);
    route_topk<<<1,128,0,stream>>>(rsum, rsum+2048, qsum,qsq,ksum,ksq,qg,qb,kg,kb,idxp);
    {
        dim3 lg(8192,3);
        lif_bn_win3<<<lg,256,0,stream>>>(qconv,kconv,x, qspk,kspk,vspk,
                                         stats, qg,qb,kg,kb,vg,vb);
    }
    attn_lif<<<512,256,0,stream>>>(qspk,kspk,vspk,idxp,out2);
    {
        dim3 gg(8,8,8);
        gemm_cp4<<<gg,256,0,stream>>>(out2, Wp2, pconv);
    }
    pstats_part<<<1024,256,0,stream>>>(pconv, ppart_sum, ppart_sq);
    pstats_fin<<<1,128,0,stream>>>(ppart_sum, ppart_sq, psum, psq);
    bn_apply<<<32768,256,0,stream>>>(pconv, out, psum, psq, pg, pb);
}

// Round 6
// 600.858 us; speedup vs baseline: 1.8190x; 1.6911x over previous
//
#include <hip/hip_runtime.h>

#define TT 4
#define BB 2
#define CC 128
#define DD 8
#define HHH 32
#define WWW 32
#define PP (DD*HHH*WWW)        // 8192
#define TSTRIDE (BB*CC*PP)     // 2097152
#define NWIN 8
#define SSS 1024
#define NHEAD 8
#define HDIM 16
#define THETA 0.7f
#define VTH 1.0f
#define NPERC (TT*BB*PP)       // 65536
#define EPSf 1e-5f

typedef unsigned short ushortT;
typedef __bf16 bf16x8 __attribute__((ext_vector_type(8)));
typedef float  f32x16 __attribute__((ext_vector_type(16)));

__device__ __forceinline__ ushortT bf16rn(float x){
    unsigned u = __float_as_uint(x);
    unsigned r = (u + 0x7FFFu + ((u>>16)&1u)) >> 16;
    return (ushortT)r;
}
__device__ __forceinline__ float bf16tof(ushortT h){
    return __uint_as_float(((unsigned)h)<<16);
}

// ---------------- wmodT: fold CDC into center tap, layout [o][tap][ic] ------
__global__ __launch_bounds__(256) void prep_wmodT(const float* __restrict__ qw,
                                                  float* __restrict__ wmodT) {
    int oi = blockIdx.x*256 + threadIdx.x;   // (o,ic)
    if (oi >= CC*CC) return;
    int o  = oi >> 7;
    int ic = oi & 127;
    const float* wp = qw + (size_t)oi*27;
    float kd = 0.f;
    #pragma unroll
    for (int t=0; t<9; t++) kd += wp[t] + wp[18+t];
    #pragma unroll
    for (int t=0; t<27; t++) {
        float v = wp[t] - ((t==13) ? THETA*kd : 0.f);
        wmodT[((size_t)o*27 + t)*CC + ic] = v;
    }
}

// ---------------- a-frag-ready split weights ---------------------------------
// wfrag[kb8][tap27][m4][split3][lane64][8 bf16]; lane: o=m*32+(lane&31),
// ic = kb*16 + (lane>>5)*8 + j
__global__ __launch_bounds__(256) void prep_wfrag(const float* __restrict__ wmodT,
                                                  ushortT* __restrict__ wfrag) {
    int id = blockIdx.x*256 + threadIdx.x;   // 8*27*4*64 = 55296
    if (id >= 8*27*4*64) return;
    int lane = id & 63;
    int r = id >> 6;
    int m = r & 3; r >>= 2;
    int t = r % 27;
    int kb = r / 27;
    int o   = m*32 + (lane & 31);
    int ic0 = kb*16 + (lane>>5)*8;
    ushortT h8[8], mm8[8], l8[8];
    #pragma unroll
    for (int j=0;j<8;j++){
        float v = wmodT[((size_t)o*27 + t)*CC + ic0 + j];
        ushortT hi = bf16rn(v);  float r1 = v - bf16tof(hi);
        ushortT mi = bf16rn(r1); float r2 = r1 - bf16tof(mi);
        ushortT lo = bf16rn(r2);
        h8[j]=hi; mm8[j]=mi; l8[j]=lo;
    }
    size_t base = ((size_t)id/64)*3*64*8 + (size_t)lane*8;   // split slot s at +s*64*8
    #pragma unroll
    for (int j=0;j<8;j++){
        wfrag[base + 0*64*8 + j] = h8[j];
        wfrag[base + 1*64*8 + j] = mm8[j];
        wfrag[base + 2*64*8 + j] = l8[j];
    }
}

// ---------------- bf16-split padded x ----------------------------------------
// xsp[tb][split3][icgrp16][dp10][hp34][wt34][ic8]; halos (dp/hp/wt = 0 or 33/9) zero
__global__ __launch_bounds__(256) void build_xsplit(const float* __restrict__ x,
                                                    ushortT* __restrict__ xsp) {
    int id = blockIdx.x*256 + threadIdx.x;   // 8*16*10*34*34 = 1479680
    if (id >= 8*16*10*34*34) return;
    int wt = id % 34; int r = id/34;
    int hp = r % 34;  r /= 34;
    int dp = r % 10;  r /= 10;
    int icg = r & 15; int tb = r >> 4;
    bool inb = (dp>=1) & (dp<=8) & (hp>=1) & (hp<=32) & (wt>=1) & (wt<=32);
    ushortT h8[8], mm8[8], l8[8];
    #pragma unroll
    for (int j=0;j<8;j++){
        float v = 0.f;
        if (inb)
            v = x[((size_t)(tb*CC + icg*8+j))*PP + (size_t)(dp-1)*1024 + (hp-1)*32 + (wt-1)];
        ushortT hi = bf16rn(v);  float r1 = v - bf16tof(hi);
        ushortT mi = bf16rn(r1); float r2 = r1 - bf16tof(mi);
        ushortT lo = bf16rn(r2);
        h8[j]=hi; mm8[j]=mi; l8[j]=lo;
    }
    // unit index for (tb,sp,icg,dp,hp,wt)
    #pragma unroll
    for (int sp=0; sp<3; sp++){
        size_t gu = (((((size_t)tb*3 + sp)*16 + icg)*10 + dp)*34 + hp)*34 + wt;
        ushortT* dst = xsp + gu*8;
        const ushortT* src = (sp==0)?h8:((sp==1)?mm8:l8);
        #pragma unroll
        for (int j=0;j<8;j++) dst[j] = src[j];
    }
}

// ---------------- conv via 32x32x16 bf16 MFMA, 6-product split ---------------
// wg: (hg,d,tb); 4 waves, wave = h-row (H0+wid), 128 o x 32 w tile.
__global__ __launch_bounds__(256) void conv_mfma(const ushortT* __restrict__ xsp,
                                                 const ushortT* __restrict__ wfrag,
                                                 float* __restrict__ y) {
    __shared__ ushortT slab[3672*8];         // 58.75 KB
    int tid  = threadIdx.x;
    int wid  = tid >> 6;
    int lane = tid & 63;
    int ln   = lane & 31;
    int half = lane >> 5;
    int hg = blockIdx.x;                     // 0..7
    int d  = blockIdx.y;                     // 0..7
    int tb = blockIdx.z;                     // 0..7
    int H0 = hg*4;

    f32x16 acc[4];
    #pragma unroll
    for (int m=0;m<4;m++)
        #pragma unroll
        for (int i=0;i<16;i++) acc[m][i] = 0.f;

    #pragma unroll 1
    for (int kb=0; kb<8; kb++) {
        __syncthreads();
        // stage slab: [split3][icg2][pos612][8ic], pos = dz*204 + hp*34 + wt
        for (int u = tid; u < 3672; u += 256) {
            int sp  = u / 1224;
            int r   = u - sp*1224;
            int icg = r / 612;
            int p   = r - icg*612;
            int dz  = p / 204;
            int r3  = p - dz*204;
            int hp  = r3 / 34;
            int wt  = r3 - hp*34;
            size_t gu = (((((size_t)tb*3 + sp)*16 + (kb*2+icg))*10 + (d+dz))*34 + (H0+hp))*34 + wt;
            *(ulonglong2*)&slab[(size_t)u*8] = *(const ulonglong2*)&xsp[gu*8];
        }
        __syncthreads();
        const ushortT* wfb = wfrag + (size_t)kb*27*4*3*64*8;
        #pragma unroll 1
        for (int t=0; t<27; t++) {
            int dz = t/9; int rr = t - dz*9; int dh = rr/3; int dw = rr - dh*3;
            int bpos = dz*204 + (wid+dh)*34 + ln + dw;
            bf16x8 bf0 = *(const bf16x8*)&slab[(((0*2 + half)*612) + bpos)*8];
            bf16x8 bf1 = *(const bf16x8*)&slab[(((1*2 + half)*612) + bpos)*8];
            bf16x8 bf2 = *(const bf16x8*)&slab[(((2*2 + half)*612) + bpos)*8];
            const ushortT* wft = wfb + (size_t)t*4*3*64*8;
            #pragma unroll
            for (int m=0; m<4; m++) {
                const ushortT* wfm = wft + (size_t)m*3*64*8 + (size_t)lane*8;
                bf16x8 a0 = *(const bf16x8*)&wfm[0*64*8];
                bf16x8 a1 = *(const bf16x8*)&wfm[1*64*8];
                bf16x8 a2 = *(const bf16x8*)&wfm[2*64*8];
                acc[m] = __builtin_amdgcn_mfma_f32_32x32x16_bf16(a0, bf0, acc[m], 0,0,0);
                acc[m] = __builtin_amdgcn_mfma_f32_32x32x16_bf16(a0, bf1, acc[m], 0,0,0);
                acc[m] = __builtin_amdgcn_mfma_f32_32x32x16_bf16(a1, bf0, acc[m], 0,0,0);
                acc[m] = __builtin_amdgcn_mfma_f32_32x32x16_bf16(a0, bf2, acc[m], 0,0,0);
                acc[m] = __builtin_amdgcn_mfma_f32_32x32x16_bf16(a1, bf1, acc[m], 0,0,0);
                acc[m] = __builtin_amdgcn_mfma_f32_32x32x16_bf16(a2, bf0, acc[m], 0,0,0);
            }
        }
    }
    int h = H0 + wid;
    #pragma unroll
    for (int m=0; m<4; m++) {
        #pragma unroll
        for (int reg=0; reg<16; reg++) {
            int row = (reg&3) + 8*(reg>>2) + 4*half;
            int o = m*32 + row;
            y[((size_t)tb*CC + o)*PP + d*1024 + h*32 + ln] = acc[m][reg];
        }
    }
}

// ---------------- pointwise weight transpose: W[o][i] -> Wt[og][i][oo16] ----
__global__ __launch_bounds__(256) void prep_cpw(const float* __restrict__ kw,
        const float* __restrict__ pw, float* __restrict__ Wk2,
        float* __restrict__ Wp2) {
    int i = blockIdx.x*256 + threadIdx.x;
    if (i >= CC*CC) return;
    int o = i >> 7, ic = i & 127;
    int dst = ((o>>4)*CC + ic)*16 + (o&15);
    Wk2[dst] = kw[i];
    Wp2[dst] = pw[i];
}

// ---------------- pointwise GEMM: float4 x, SGPR weights --------------------
__global__ __launch_bounds__(256) void gemm_cp4(const float* __restrict__ xin,
                                                const float* __restrict__ Wt,
                                                float* __restrict__ y) {
    int tid  = threadIdx.x;
    int tile = blockIdx.x, og = blockIdx.y, tb = blockIdx.z;
    const float* xb = xin + (size_t)tb*CC*PP + tile*1024 + tid*4;
    const float* wp = Wt + (size_t)og*CC*16;
    float acc[16][4];
    #pragma unroll
    for (int oo=0;oo<16;oo++)
        #pragma unroll
        for (int j=0;j<4;j++) acc[oo][j]=0.f;
    #pragma unroll 2
    for (int i=0;i<CC;i++){
        float4 xv = *(const float4*)(xb + (size_t)i*PP);
        const float* wv = wp + i*16;
        #pragma unroll
        for (int oo=0;oo<16;oo++){
            acc[oo][0] += wv[oo]*xv.x;
            acc[oo][1] += wv[oo]*xv.y;
            acc[oo][2] += wv[oo]*xv.z;
            acc[oo][3] += wv[oo]*xv.w;
        }
    }
    #pragma unroll
    for (int oo=0;oo<16;oo++){
        float4 o4;
        o4.x=acc[oo][0]; o4.y=acc[oo][1]; o4.z=acc[oo][2]; o4.w=acc[oo][3];
        *(float4*)&y[((size_t)tb*CC + og*16+oo)*PP + tile*1024 + tid*4] = o4;
    }
}

// ---------------- per-(src,b,win,c) sum & sumsq partials ---------------------
__global__ __launch_bounds__(128) void win_stats(const float* __restrict__ q,
        const float* __restrict__ k, const float* __restrict__ x,
        float* __restrict__ rsum, float* __restrict__ rsq) {
    int blk = blockIdx.x;
    int src = blk >> 11;
    int r   = blk & 2047;
    const float* base = (src==0) ? q : ((src==1) ? k : x);
    int c  = r & 127;
    int wi = (r >> 7) & 7;
    int b  = r >> 10;
    int wd = wi>>2, wh = (wi>>1)&1, ww = wi&1;
    int tid = threadIdx.x;
    float s=0.f, s2=0.f;
    for (int t=0;t<TT;t++){
        const float* p = base + ((size_t)(t*BB+b)*CC + c)*PP;
        for (int si=tid; si<SSS; si+=128){
            int ld = si>>8, lh=(si>>4)&15, lw=si&15;
            float v = p[((wd*4+ld)<<10) + ((wh*16+lh)<<5) + (ww*16+lw)];
            s += v; s2 += v*v;
        }
    }
    __shared__ float ls[128], ls2[128];
    ls[tid]=s; ls2[tid]=s2; __syncthreads();
    for (int off=64;off>0;off>>=1){
        if(tid<off){ ls[tid]+=ls[tid+off]; ls2[tid]+=ls2[tid+off]; }
        __syncthreads();
    }
    if (tid==0){ rsum[blk]=ls[0]; rsq[blk]=ls2[0]; }
}

// ---------------- finalize per-channel stats for q,k,v ----------------------
__global__ __launch_bounds__(384) void stats_fin(const float* __restrict__ rsum,
        const float* __restrict__ rsq, float* __restrict__ sums) {
    int tid = threadIdx.x;
    int src = tid >> 7, c = tid & 127;
    float s=0.f, s2=0.f;
    for (int bw=0; bw<16; bw++){
        int idx = src*2048 + bw*128 + c;
        s  += rsum[idx];
        s2 += rsq[idx];
    }
    sums[src*256 + c]       = s;
    sums[src*256 + 128 + c] = s2;
}

// ---------------- routing: normalize regions, a_r, top-4 --------------------
__global__ __launch_bounds__(128) void route_topk(const float* __restrict__ qreg,
        const float* __restrict__ kreg,
        const float* __restrict__ qsum, const float* __restrict__ qsq,
        const float* __restrict__ ksum, const float* __restrict__ ksq,
        const float* __restrict__ qg, const float* __restrict__ qb,
        const float* __restrict__ kg, const float* __restrict__ kb,
        int* __restrict__ idxout) {
    __shared__ float qn[16*128], kn[16*128], ar[16*8];
    int tid = threadIdx.x;
    for (int e=tid; e<16*128; e+=128){
        int c = e&127;
        float qm = qsum[c]*(1.f/NPERC);
        float qv = qsq[c]*(1.f/NPERC) - qm*qm;
        float qr = rsqrtf(qv + EPSf);
        qn[e] = (qreg[e]*(1.f/(TT*SSS)) - qm)*qr*qg[c] + qb[c];
        float km = ksum[c]*(1.f/NPERC);
        float kv = ksq[c]*(1.f/NPERC) - km*km;
        float kr = rsqrtf(kv + EPSf);
        kn[e] = (kreg[e]*(1.f/(TT*SSS)) - km)*kr*kg[c] + kb[c];
    }
    __syncthreads();
    {
        int b = tid>>6, w=(tid>>3)&7, v=tid&7;
        float s=0.f;
        for (int c=0;c<128;c++) s += qn[(b*8+w)*128+c]*kn[(b*8+v)*128+c];
        ar[(b*8+w)*8+v] = s * 0.25f;
    }
    __syncthreads();
    if (tid < 16){
        const float* row = &ar[tid*8];
        bool used[8] = {false,false,false,false,false,false,false,false};
        for (int j=0;j<4;j++){
            int best=0; float bv=-3.0e38f;
            for (int v=0; v<8; v++){
                if (!used[v] && row[v] > bv){ bv=row[v]; best=v; }
            }
            used[best]=true;
            idxout[tid*4+j]=best;
        }
    }
}

// ---------------- LIF+BN for q,k,v in ONE launch (grid.y = src) -------------
__global__ __launch_bounds__(256) void lif_bn_win3(const float* __restrict__ qin,
        const float* __restrict__ kin, const float* __restrict__ xin,
        float* __restrict__ qs, float* __restrict__ ks, float* __restrict__ vs,
        const float* __restrict__ stats,
        const float* __restrict__ qg, const float* __restrict__ qb,
        const float* __restrict__ kg, const float* __restrict__ kb,
        const float* __restrict__ vg, const float* __restrict__ vb) {
    int src = blockIdx.y;
    const float* in  = (src==0) ? qin : ((src==1) ? kin : xin);
    float*       spk = (src==0) ? qs  : ((src==1) ? ks  : vs);
    const float* gamma = (src==0) ? qg : ((src==1) ? kg : vg);
    const float* beta  = (src==0) ? qb : ((src==1) ? kb : vb);
    int e = blockIdx.x*256 + threadIdx.x;
    if (e >= BB*CC*PP) return;
    int p = e & (PP-1);
    int c = (e >> 13) & 127;
    int b = e >> 20;
    float mean = stats[src*256 + c]*(1.f/NPERC);
    float var  = stats[src*256 + 128 + c]*(1.f/NPERC) - mean*mean;
    float sc = rsqrtf(var+EPSf)*gamma[c];
    float sh = beta[c] - mean*sc;
    int d = p>>10, h=(p>>5)&31, w=p&31;
    int wi = ((d>>2)*2 + (h>>4))*2 + (w>>4);
    int si = (((d&3)<<4) + (h&15))*16 + (w&15);
    size_t widx = ((size_t)(b*NWIN+wi)*CC + c)*SSS + si;
    float v=0.f;
    #pragma unroll
    for (int t=0;t<TT;t++){
        float xn = in[(size_t)t*TSTRIDE + e]*sc + sh;
        v = (v+xn)*0.5f;
        float s = (v>=VTH)?1.f:0.f;
        spk[(size_t)t*TSTRIDE + widx] = s;
        v *= (1.f - s);
    }
}

// ---------------- window attention + fused output LIF -> standard layout ----
__global__ __launch_bounds__(256) void attn_lif(const float* __restrict__ qspk,
        const float* __restrict__ kspk, const float* __restrict__ vspk,
        const int* __restrict__ idx, float* __restrict__ out2) {
    int id = blockIdx.x*256 + threadIdx.x;   // B*W*H*S = 131072
    if (id >= BB*NWIN*NHEAD*SSS) return;
    int s  = id & 1023;
    int hh = (id>>10) & 7;
    int wi = (id>>13) & 7;
    int b  = id>>16;
    int bw = b*NWIN+wi;
    size_t qbase = ((size_t)bw*CC + hh*HDIM)*SSS + s;
    size_t sbase[4];
    #pragma unroll
    for (int j=0;j<4;j++){
        int src = idx[bw*4+j];
        sbase[j] = ((size_t)(b*NWIN+src)*CC + hh*HDIM)*SSS + s;
    }
    int wd = wi>>2, wh = (wi>>1)&1, ww = wi&1;
    int d3 = wd*4 + (s>>8), h3 = wh*16 + ((s>>4)&15), w3 = ww*16 + (s&15);
    int p  = (d3<<10) + (h3<<5) + w3;
    size_t obase = ((size_t)b*CC + hh*HDIM)*PP + p;

    float v=0.f;
    float v2[16];
    #pragma unroll
    for (int dd=0; dd<16; dd++) v2[dd]=0.f;

    #pragma unroll 1
    for (int t=0;t<TT;t++){
        size_t toff = (size_t)t*TSTRIDE;
        float km[16], vm[16];
        #pragma unroll
        for (int dd=0;dd<16;dd++){ km[dd]=0.f; vm[dd]=0.f; }
        #pragma unroll
        for (int j=0;j<4;j++){
            const float* kp = kspk+toff+sbase[j];
            const float* vp = vspk+toff+sbase[j];
            #pragma unroll
            for (int dd=0; dd<16; dd++){
                km[dd] += kp[(size_t)dd*SSS];
                vm[dd] += vp[(size_t)dd*SSS];
            }
        }
        const float* qp = qspk+toff+qbase;
        float att=0.f;
        #pragma unroll
        for (int dd=0;dd<16;dd++) att += qp[(size_t)dd*SSS]*km[dd];
        att *= 0.25f;
        v = (v+att)*0.5f;
        float sp = (v>=VTH)?1.f:0.f;
        v *= (1.f-sp);
        float spq = sp*0.25f;
        float* op = out2 + toff + obase;
        #pragma unroll
        for (int dd=0;dd<16;dd++){
            float ov = spq*vm[dd];
            v2[dd] = (v2[dd]+ov)*0.5f;
            float s2 = (v2[dd]>=VTH)?1.f:0.f;
            v2[dd] *= (1.f-s2);
            op[(size_t)dd*PP] = s2;
        }
    }
}

// ---------------- p-stats: partials over (tb,c), then finalize ---------------
__global__ __launch_bounds__(256) void pstats_part(const float* __restrict__ xin,
        float* __restrict__ part_sum, float* __restrict__ part_sq) {
    int blk = blockIdx.x;                    // tb*128 + c
    int c = blk & 127, tb = blk >> 7;
    int tid = threadIdx.x;
    const float* p = xin + ((size_t)tb*CC + c)*PP;
    float s=0.f, s2=0.f;
    for (int i=tid; i<PP; i+=256){ float v=p[i]; s+=v; s2+=v*v; }
    __shared__ float ls[256], ls2[256];
    ls[tid]=s; ls2[tid]=s2; __syncthreads();
    for (int off=128; off>0; off>>=1){
        if (tid<off){ ls[tid]+=ls[tid+off]; ls2[tid]+=ls2[tid+off]; }
        __syncthreads();
    }
    if (tid==0){ part_sum[blk]=ls[0]; part_sq[blk]=ls2[0]; }
}

__global__ __launch_bounds__(128) void pstats_fin(const float* __restrict__ part_sum,
        const float* __restrict__ part_sq, float* __restrict__ sum,
        float* __restrict__ sq) {
    int c = threadIdx.x;
    float s=0.f, s2=0.f;
    for (int tb=0; tb<8; tb++){
        s  += part_sum[tb*128+c];
        s2 += part_sq[tb*128+c];
    }
    sum[c]=s; sq[c]=s2;
}

// ---------------- final BN apply ---------------------------------------------
__global__ __launch_bounds__(256) void bn_apply(const float* __restrict__ xin,
        float* __restrict__ yout,
        const float* __restrict__ sum, const float* __restrict__ sq,
        const float* __restrict__ gamma, const float* __restrict__ beta) {
    size_t i = (size_t)blockIdx.x*256 + threadIdx.x;
    if (i >= (size_t)TT*BB*CC*PP) return;
    int c = (int)((i>>13)&127);
    float mean = sum[c]*(1.f/NPERC);
    float var  = sq[c]*(1.f/NPERC) - mean*mean;
    float sc = rsqrtf(var+EPSf)*gamma[c];
    float sh = beta[c] - mean*sc;
    yout[i] = xin[i]*sc + sh;
}

extern "C" void kernel_launch(void* const* d_in, const int* in_sizes, int n_in,
                              void* d_out, int out_size, void* d_ws, size_t ws_size,
                              hipStream_t stream) {
    const float* x  = (const float*)d_in[0];
    const float* qw = (const float*)d_in[1];
    const float* qg = (const float*)d_in[2];
    const float* qb = (const float*)d_in[3];
    const float* kw = (const float*)d_in[4];
    const float* kg = (const float*)d_in[5];
    const float* kb = (const float*)d_in[6];
    const float* vg = (const float*)d_in[7];
    const float* vb = (const float*)d_in[8];
    const float* pw = (const float*)d_in[9];
    const float* pg = (const float*)d_in[10];
    const float* pb = (const float*)d_in[11];
    float* out = (float*)d_out;
    float* ws  = (float*)d_ws;

    const size_t NEL = (size_t)TT*TSTRIDE;   // 8388608
    float* qconv = ws;
    float* kconv = ws + NEL;
    float* qspk  = ws + 2*NEL;
    float* kspk  = ws + 3*NEL;
    float* vspk  = ws + 4*NEL;
    float* wmodT = ws + 5*NEL;               // 442368 floats
    float* stats = ws + 5*NEL + 442368;
    float *qsum=stats,     *qsq=stats+128,  *ksum=stats+256, *ksq=stats+384,
          *psum=stats+768, *psq=stats+896;
    float* rsum = stats + 1024;              // 6144
    float* rsq  = rsum + 6144;               // 6144
    float* ppart_sum = rsq + 6144;           // 1024
    float* ppart_sq  = ppart_sum + 1024;     // 1024
    int*   idxp = (int*)(ppart_sq + 1024);   // 64 ints
    float* Wk2 = stats + 16384;              // 16384
    float* Wp2 = Wk2 + 16384;                // 16384

    // lifetimes: xsplit (71MB) overlays qspk+kspk(+tail) until conv done;
    // wfrag (2.65MB) overlays vspk start until conv done.
    ushortT* xsp   = (ushortT*)(ws + 2*NEL);
    ushortT* wfrag = (ushortT*)(ws + 4*NEL);
    float* out2  = kconv;                    // kconv dead after lif(k)
    float* pconv = qspk;                     // qspk dead after attn

    prep_wmodT<<<64,256,0,stream>>>(qw, wmodT);
    prep_wfrag<<<216,256,0,stream>>>(wmodT, wfrag);
    prep_cpw<<<64,256,0,stream>>>(kw, pw, Wk2, Wp2);
    build_xsplit<<<5780,256,0,stream>>>(x, xsp);
    {
        dim3 gg(8,8,8);
        gemm_cp4<<<gg,256,0,stream>>>(x, Wk2, kconv);
        conv_mfma<<<gg,256,0,stream>>>(xsp, wfrag, qconv);
    }
    win_stats<<<6144,128,0,stream>>>(qconv, kconv, x, rsum, rsq);
    stats_fin<<<1,384,0,stream>>>(rsum, rsq, stats);
    route_topk<<<1,128,0,stream>>>(rsum, rsum+2048, qsum,qsq,ksum,ksq,qg,qb,kg,kb,idxp);
    {
        dim3 lg(8192,3);
        lif_bn_win3<<<lg,256,0,stream>>>(qconv,kconv,x, qspk,kspk,vspk,
                                         stats, qg,qb,kg,kb,vg,vb);
    }
    attn_lif<<<512,256,0,stream>>>(qspk,kspk,vspk,idxp,out2);
    {
        dim3 gg(8,8,8);
        gemm_cp4<<<gg,256,0,stream>>>(out2, Wp2, pconv);
    }
    pstats_part<<<1024,256,0,stream>>>(pconv, ppart_sum, ppart_sq);
    pstats_fin<<<1,128,0,stream>>>(ppart_sum, ppart_sq, psum, psq);
    bn_apply<<<32768,256,0,stream>>>(pconv, out, psum, psq, pg, pb);
}

// Round 7
// 542.438 us; speedup vs baseline: 2.0149x; 1.1077x over previous
//
#include <hip/hip_runtime.h>

#define TT 4
#define BB 2
#define CC 128
#define DD 8
#define HHH 32
#define WWW 32
#define PP (DD*HHH*WWW)        // 8192
#define TSTRIDE (BB*CC*PP)     // 2097152
#define NWIN 8
#define SSS 1024
#define NHEAD 8
#define HDIM 16
#define THETA 0.7f
#define VTH 1.0f
#define NPERC (TT*BB*PP)       // 65536
#define EPSf 1e-5f

typedef unsigned short ushortT;
typedef __bf16 bf16x8 __attribute__((ext_vector_type(8)));
typedef float  f32x16 __attribute__((ext_vector_type(16)));

__device__ __forceinline__ ushortT bf16rn(float x){
    unsigned u = __float_as_uint(x);
    unsigned r = (u + 0x7FFFu + ((u>>16)&1u)) >> 16;
    return (ushortT)r;
}
__device__ __forceinline__ float bf16tof(ushortT h){
    return __uint_as_float(((unsigned)h)<<16);
}

// ---------------- wmodT: fold CDC into center tap, layout [o][tap][ic] ------
__global__ __launch_bounds__(256) void prep_wmodT(const float* __restrict__ qw,
                                                  float* __restrict__ wmodT) {
    int oi = blockIdx.x*256 + threadIdx.x;
    if (oi >= CC*CC) return;
    int o  = oi >> 7;
    int ic = oi & 127;
    const float* wp = qw + (size_t)oi*27;
    float kd = 0.f;
    #pragma unroll
    for (int t=0; t<9; t++) kd += wp[t] + wp[18+t];
    #pragma unroll
    for (int t=0; t<27; t++) {
        float v = wp[t] - ((t==13) ? THETA*kd : 0.f);
        wmodT[((size_t)o*27 + t)*CC + ic] = v;
    }
}

// ---------------- conv a-frag split weights ---------------------------------
// wfrag[kb8][tap27][m4][split3][lane64][8]
__global__ __launch_bounds__(256) void prep_wfrag(const float* __restrict__ wmodT,
                                                  ushortT* __restrict__ wfrag) {
    int id = blockIdx.x*256 + threadIdx.x;   // 8*27*4*64 = 55296
    if (id >= 8*27*4*64) return;
    int lane = id & 63;
    int r = id >> 6;
    int m = r & 3; r >>= 2;
    int t = r % 27;
    int kb = r / 27;
    int o   = m*32 + (lane & 31);
    int ic0 = kb*16 + (lane>>5)*8;
    size_t base = ((size_t)(id>>6))*3*64*8 + (size_t)lane*8;
    #pragma unroll
    for (int j=0;j<8;j++){
        float v = wmodT[((size_t)o*27 + t)*CC + ic0 + j];
        ushortT hi = bf16rn(v);  float r1 = v - bf16tof(hi);
        ushortT mi = bf16rn(r1); float r2 = r1 - bf16tof(mi);
        ushortT lo = bf16rn(r2);
        wfrag[base + 0*64*8 + j] = hi;
        wfrag[base + 1*64*8 + j] = mi;
        wfrag[base + 2*64*8 + j] = lo;
    }
}

// ---------------- 1x1 weight split frags: frag[kb8][m4][sp3][lane64][8] -----
__global__ __launch_bounds__(256) void prep_w1frag(const float* __restrict__ W,
                                                   ushortT* __restrict__ frag) {
    int id = blockIdx.x*256 + threadIdx.x;   // 8*4*64 = 2048
    if (id >= 2048) return;
    int lane = id & 63;
    int r = id >> 6;
    int m = r & 3;
    int kb = r >> 2;
    int o   = m*32 + (lane & 31);
    int ic0 = kb*16 + (lane>>5)*8;
    size_t base = ((size_t)(kb*4+m))*3*64*8 + (size_t)lane*8;
    #pragma unroll
    for (int j=0;j<8;j++){
        float v = W[(size_t)o*CC + ic0 + j];
        ushortT hi = bf16rn(v);  float r1 = v - bf16tof(hi);
        ushortT mi = bf16rn(r1); float r2 = r1 - bf16tof(mi);
        ushortT lo = bf16rn(r2);
        frag[base + 0*64*8 + j] = hi;
        frag[base + 1*64*8 + j] = mi;
        frag[base + 2*64*8 + j] = lo;
    }
}

// ---------------- bf16-split padded x (h/w halos only, no d halo) -----------
// xsp[tb][sp3][icg16][d8][hp34][wt34][ic8]; hp/wt 0,33 are zero halos
__global__ __launch_bounds__(256) void build_xsplit(const float* __restrict__ x,
                                                    ushortT* __restrict__ xsp) {
    int id = blockIdx.x*256 + threadIdx.x;   // 8*16*8*34*34 = 1,183,744
    if (id >= 8*16*8*34*34) return;
    int wt = id % 34; int r = id/34;
    int hp = r % 34;  r /= 34;
    int dz = r % 8;   r /= 8;
    int icg = r & 15; int tb = r >> 4;
    bool inb = (hp>=1) & (hp<=32) & (wt>=1) & (wt<=32);
    ushortT h8[8], mm8[8], l8[8];
    #pragma unroll
    for (int j=0;j<8;j++){
        float v = 0.f;
        if (inb)
            v = x[((size_t)(tb*CC + icg*8+j))*PP + (size_t)dz*1024 + (hp-1)*32 + (wt-1)];
        ushortT hi = bf16rn(v);  float r1 = v - bf16tof(hi);
        ushortT mi = bf16rn(r1); float r2 = r1 - bf16tof(mi);
        ushortT lo = bf16rn(r2);
        h8[j]=hi; mm8[j]=mi; l8[j]=lo;
    }
    #pragma unroll
    for (int sp=0; sp<3; sp++){
        size_t gu = (((((size_t)tb*3 + sp)*16 + icg)*8 + dz)*34 + hp)*34 + wt;
        ushortT* dst = xsp + gu*8;
        const ushortT* src = (sp==0)?h8:((sp==1)?mm8:l8);
        #pragma unroll
        for (int j=0;j<8;j++) dst[j] = src[j];
    }
}

// ---------------- conv via 32x32x16 bf16 MFMA, software-pipelined -----------
__global__ __launch_bounds__(256) void conv_mfma(const ushortT* __restrict__ xsp,
                                                 const ushortT* __restrict__ wfrag,
                                                 float* __restrict__ y) {
    __shared__ ushortT slab[3672*8];         // 58.75 KB
    int tid  = threadIdx.x;
    int wid  = tid >> 6;
    int lane = tid & 63;
    int ln   = lane & 31;
    int half = lane >> 5;
    int hg = blockIdx.x;
    int d  = blockIdx.y;
    int tb = blockIdx.z;
    int H0 = hg*4;

    f32x16 acc[4];
    #pragma unroll
    for (int m=0;m<4;m++)
        #pragma unroll
        for (int i=0;i<16;i++) acc[m][i] = 0.f;

    // current a-frags (kb=0, t=0), prefetched before first stage
    bf16x8 ca[4][3];
    #pragma unroll
    for (int m=0;m<4;m++)
        #pragma unroll
        for (int sp=0;sp<3;sp++)
            ca[m][sp] = *(const bf16x8*)&wfrag[((((size_t)m)*3+sp)*64 + lane)*8];

    #pragma unroll 1
    for (int kb=0; kb<8; kb++) {
        __syncthreads();
        // stage slab: [split3][icg2][pos612][8ic], pos = dz*204 + hp*34 + wt
        for (int u = tid; u < 3672; u += 256) {
            int sp  = u / 1224;
            int r   = u - sp*1224;
            int icg = r / 612;
            int p   = r - icg*612;
            int dz  = p / 204;
            int r3  = p - dz*204;
            int hp  = r3 / 34;
            int wt  = r3 - hp*34;
            int dd  = d - 1 + dz;
            ulonglong2 v; v.x = 0; v.y = 0;
            if ((unsigned)dd < 8u) {
                size_t gu = (((((size_t)tb*3 + sp)*16 + (kb*2+icg))*8 + dd)*34 + (H0+hp))*34 + wt;
                v = *(const ulonglong2*)&xsp[gu*8];
            }
            *(ulonglong2*)&slab[(size_t)u*8] = v;
        }
        __syncthreads();
        // b-frags for t=0
        bf16x8 cb[3];
        {
            int bpos = (wid)*34 + ln;        // dz=0,dh=0,dw=0
            #pragma unroll
            for (int sp=0;sp<3;sp++)
                cb[sp] = *(const bf16x8*)&slab[(size_t)((sp*2+half)*612 + bpos)*8];
        }
        #pragma unroll 1
        for (int t=0; t<27; t++) {
            bf16x8 nb[3], na[4][3];
            int nt  = (t<26)? t+1 : 0;
            int nkb = (t<26)? kb  : ((kb<7)? kb+1 : 7);
            {
                int dz=nt/9; int rr=nt-dz*9; int dh=rr/3; int dw=rr-dh*3;
                int bpos = dz*204 + (wid+dh)*34 + ln + dw;
                #pragma unroll
                for (int sp=0;sp<3;sp++)
                    nb[sp] = *(const bf16x8*)&slab[(size_t)((sp*2+half)*612 + bpos)*8];
            }
            #pragma unroll
            for (int m=0;m<4;m++)
                #pragma unroll
                for (int sp=0;sp<3;sp++)
                    na[m][sp] = *(const bf16x8*)&wfrag[((((size_t)(nkb*27+nt)*4+m)*3+sp)*64 + lane)*8];
            // 6 split terms, term-outer (per-acc order unchanged vs R6)
            #pragma unroll
            for (int m=0;m<4;m++) acc[m] = __builtin_amdgcn_mfma_f32_32x32x16_bf16(ca[m][0], cb[0], acc[m],0,0,0);
            #pragma unroll
            for (int m=0;m<4;m++) acc[m] = __builtin_amdgcn_mfma_f32_32x32x16_bf16(ca[m][0], cb[1], acc[m],0,0,0);
            #pragma unroll
            for (int m=0;m<4;m++) acc[m] = __builtin_amdgcn_mfma_f32_32x32x16_bf16(ca[m][1], cb[0], acc[m],0,0,0);
            #pragma unroll
            for (int m=0;m<4;m++) acc[m] = __builtin_amdgcn_mfma_f32_32x32x16_bf16(ca[m][0], cb[2], acc[m],0,0,0);
            #pragma unroll
            for (int m=0;m<4;m++) acc[m] = __builtin_amdgcn_mfma_f32_32x32x16_bf16(ca[m][1], cb[1], acc[m],0,0,0);
            #pragma unroll
            for (int m=0;m<4;m++) acc[m] = __builtin_amdgcn_mfma_f32_32x32x16_bf16(ca[m][2], cb[0], acc[m],0,0,0);
            #pragma unroll
            for (int m=0;m<4;m++)
                #pragma unroll
                for (int sp=0;sp<3;sp++) ca[m][sp] = na[m][sp];
            #pragma unroll
            for (int sp=0;sp<3;sp++) cb[sp] = nb[sp];
        }
    }
    int h = H0 + wid;
    #pragma unroll
    for (int m=0; m<4; m++) {
        #pragma unroll
        for (int reg=0; reg<16; reg++) {
            int row = (reg&3) + 8*(reg>>2) + 4*half;
            int o = m*32 + row;
            y[((size_t)tb*CC + o)*PP + d*1024 + h*32 + ln] = acc[m][reg];
        }
    }
}

// ---------------- k-gemm (1x1) via MFMA, 6-term split, reads xsp ------------
__global__ __launch_bounds__(256) void kgemm_mfma(const ushortT* __restrict__ xsp,
                                                  const ushortT* __restrict__ wk,
                                                  float* __restrict__ y) {
    int tid  = threadIdx.x;
    int wid  = tid >> 6;
    int lane = tid & 63;
    int ln   = lane & 31;
    int half = lane >> 5;
    int hg = blockIdx.x, d = blockIdx.y, tb = blockIdx.z;
    int h = hg*4 + wid;

    f32x16 acc[4];
    #pragma unroll
    for (int m=0;m<4;m++)
        #pragma unroll
        for (int i=0;i<16;i++) acc[m][i] = 0.f;

    #pragma unroll 2
    for (int kb=0; kb<8; kb++) {
        bf16x8 b[3];
        #pragma unroll
        for (int sp=0; sp<3; sp++) {
            size_t gu = (((((size_t)tb*3 + sp)*16 + (kb*2+half))*8 + d)*34 + (h+1))*34 + (ln+1);
            b[sp] = *(const bf16x8*)&xsp[gu*8];
        }
        #pragma unroll
        for (int m=0; m<4; m++) {
            const ushortT* wb = wk + ((size_t)(kb*4+m))*3*64*8 + (size_t)lane*8;
            bf16x8 a0 = *(const bf16x8*)&wb[0*64*8];
            bf16x8 a1 = *(const bf16x8*)&wb[1*64*8];
            bf16x8 a2 = *(const bf16x8*)&wb[2*64*8];
            acc[m] = __builtin_amdgcn_mfma_f32_32x32x16_bf16(a0, b[0], acc[m],0,0,0);
            acc[m] = __builtin_amdgcn_mfma_f32_32x32x16_bf16(a0, b[1], acc[m],0,0,0);
            acc[m] = __builtin_amdgcn_mfma_f32_32x32x16_bf16(a1, b[0], acc[m],0,0,0);
            acc[m] = __builtin_amdgcn_mfma_f32_32x32x16_bf16(a0, b[2], acc[m],0,0,0);
            acc[m] = __builtin_amdgcn_mfma_f32_32x32x16_bf16(a1, b[1], acc[m],0,0,0);
            acc[m] = __builtin_amdgcn_mfma_f32_32x32x16_bf16(a2, b[0], acc[m],0,0,0);
        }
    }
    #pragma unroll
    for (int m=0; m<4; m++) {
        #pragma unroll
        for (int reg=0; reg<16; reg++) {
            int row = (reg&3) + 8*(reg>>2) + 4*half;
            int o = m*32 + row;
            y[((size_t)tb*CC + o)*PP + d*1024 + h*32 + ln] = acc[m][reg];
        }
    }
}

// ---------------- p-gemm via MFMA: exact bf16 spikes x 3-split weights ------
__global__ __launch_bounds__(256) void pgemm_mfma(const ushortT* __restrict__ spkb,
                                                  const ushortT* __restrict__ wp,
                                                  float* __restrict__ y) {
    int tid  = threadIdx.x;
    int wid  = tid >> 6;
    int lane = tid & 63;
    int ln   = lane & 31;
    int half = lane >> 5;
    int hg = blockIdx.x, d = blockIdx.y, tb = blockIdx.z;
    int h = hg*4 + wid;
    int p = d*1024 + h*32 + ln;

    f32x16 acc[4];
    #pragma unroll
    for (int m=0;m<4;m++)
        #pragma unroll
        for (int i=0;i<16;i++) acc[m][i] = 0.f;

    #pragma unroll 2
    for (int kb=0; kb<8; kb++) {
        bf16x8 b = *(const bf16x8*)&spkb[(((size_t)tb*16 + (kb*2+half))*PP + p)*8];
        #pragma unroll
        for (int m=0; m<4; m++) {
            const ushortT* wb = wp + ((size_t)(kb*4+m))*3*64*8 + (size_t)lane*8;
            bf16x8 a0 = *(const bf16x8*)&wb[0*64*8];
            bf16x8 a1 = *(const bf16x8*)&wb[1*64*8];
            bf16x8 a2 = *(const bf16x8*)&wb[2*64*8];
            acc[m] = __builtin_amdgcn_mfma_f32_32x32x16_bf16(a0, b, acc[m],0,0,0);
            acc[m] = __builtin_amdgcn_mfma_f32_32x32x16_bf16(a1, b, acc[m],0,0,0);
            acc[m] = __builtin_amdgcn_mfma_f32_32x32x16_bf16(a2, b, acc[m],0,0,0);
        }
    }
    #pragma unroll
    for (int m=0; m<4; m++) {
        #pragma unroll
        for (int reg=0; reg<16; reg++) {
            int row = (reg&3) + 8*(reg>>2) + 4*half;
            int o = m*32 + row;
            y[((size_t)tb*CC + o)*PP + p] = acc[m][reg];
        }
    }
}

// ---------------- per-(src,b,win,c) sum & sumsq partials ---------------------
__global__ __launch_bounds__(128) void win_stats(const float* __restrict__ q,
        const float* __restrict__ k, const float* __restrict__ x,
        float* __restrict__ rsum, float* __restrict__ rsq) {
    int blk = blockIdx.x;
    int src = blk >> 11;
    int r   = blk & 2047;
    const float* base = (src==0) ? q : ((src==1) ? k : x);
    int c  = r & 127;
    int wi = (r >> 7) & 7;
    int b  = r >> 10;
    int wd = wi>>2, wh = (wi>>1)&1, ww = wi&1;
    int tid = threadIdx.x;
    float s=0.f, s2=0.f;
    for (int t=0;t<TT;t++){
        const float* p = base + ((size_t)(t*BB+b)*CC + c)*PP;
        for (int si=tid; si<SSS; si+=128){
            int ld = si>>8, lh=(si>>4)&15, lw=si&15;
            float v = p[((wd*4+ld)<<10) + ((wh*16+lh)<<5) + (ww*16+lw)];
            s += v; s2 += v*v;
        }
    }
    __shared__ float ls[128], ls2[128];
    ls[tid]=s; ls2[tid]=s2; __syncthreads();
    for (int off=64;off>0;off>>=1){
        if(tid<off){ ls[tid]+=ls[tid+off]; ls2[tid]+=ls2[tid+off]; }
        __syncthreads();
    }
    if (tid==0){ rsum[blk]=ls[0]; rsq[blk]=ls2[0]; }
}

// ---------------- finalize per-channel stats for q,k,v ----------------------
__global__ __launch_bounds__(384) void stats_fin(const float* __restrict__ rsum,
        const float* __restrict__ rsq, float* __restrict__ sums) {
    int tid = threadIdx.x;
    int src = tid >> 7, c = tid & 127;
    float s=0.f, s2=0.f;
    for (int bw=0; bw<16; bw++){
        int idx = src*2048 + bw*128 + c;
        s  += rsum[idx];
        s2 += rsq[idx];
    }
    sums[src*256 + c]       = s;
    sums[src*256 + 128 + c] = s2;
}

// ---------------- routing: normalize regions, a_r, top-4 --------------------
__global__ __launch_bounds__(128) void route_topk(const float* __restrict__ qreg,
        const float* __restrict__ kreg,
        const float* __restrict__ qsum, const float* __restrict__ qsq,
        const float* __restrict__ ksum, const float* __restrict__ ksq,
        const float* __restrict__ qg, const float* __restrict__ qb,
        const float* __restrict__ kg, const float* __restrict__ kb,
        int* __restrict__ idxout) {
    __shared__ float qn[16*128], kn[16*128], ar[16*8];
    int tid = threadIdx.x;
    for (int e=tid; e<16*128; e+=128){
        int c = e&127;
        float qm = qsum[c]*(1.f/NPERC);
        float qv = qsq[c]*(1.f/NPERC) - qm*qm;
        float qr = rsqrtf(qv + EPSf);
        qn[e] = (qreg[e]*(1.f/(TT*SSS)) - qm)*qr*qg[c] + qb[c];
        float km = ksum[c]*(1.f/NPERC);
        float kv = ksq[c]*(1.f/NPERC) - km*km;
        float kr = rsqrtf(kv + EPSf);
        kn[e] = (kreg[e]*(1.f/(TT*SSS)) - km)*kr*kg[c] + kb[c];
    }
    __syncthreads();
    {
        int b = tid>>6, w=(tid>>3)&7, v=tid&7;
        float s=0.f;
        for (int c=0;c<128;c++) s += qn[(b*8+w)*128+c]*kn[(b*8+v)*128+c];
        ar[(b*8+w)*8+v] = s * 0.25f;
    }
    __syncthreads();
    if (tid < 16){
        const float* row = &ar[tid*8];
        bool used[8] = {false,false,false,false,false,false,false,false};
        for (int j=0;j<4;j++){
            int best=0; float bv=-3.0e38f;
            for (int v=0; v<8; v++){
                if (!used[v] && row[v] > bv){ bv=row[v]; best=v; }
            }
            used[best]=true;
            idxout[tid*4+j]=best;
        }
    }
}

// ---------------- LIF+BN for q,k,v in ONE launch (grid.y = src) -------------
__global__ __launch_bounds__(256) void lif_bn_win3(const float* __restrict__ qin,
        const float* __restrict__ kin, const float* __restrict__ xin,
        float* __restrict__ qs, float* __restrict__ ks, float* __restrict__ vs,
        const float* __restrict__ stats,
        const float* __restrict__ qg, const float* __restrict__ qb,
        const float* __restrict__ kg, const float* __restrict__ kb,
        const float* __restrict__ vg, const float* __restrict__ vb) {
    int src = blockIdx.y;
    const float* in  = (src==0) ? qin : ((src==1) ? kin : xin);
    float*       spk = (src==0) ? qs  : ((src==1) ? ks  : vs);
    const float* gamma = (src==0) ? qg : ((src==1) ? kg : vg);
    const float* beta  = (src==0) ? qb : ((src==1) ? kb : vb);
    int e = blockIdx.x*256 + threadIdx.x;
    if (e >= BB*CC*PP) return;
    int p = e & (PP-1);
    int c = (e >> 13) & 127;
    int b = e >> 20;
    float mean = stats[src*256 + c]*(1.f/NPERC);
    float var  = stats[src*256 + 128 + c]*(1.f/NPERC) - mean*mean;
    float sc = rsqrtf(var+EPSf)*gamma[c];
    float sh = beta[c] - mean*sc;
    int d = p>>10, h=(p>>5)&31, w=p&31;
    int wi = ((d>>2)*2 + (h>>4))*2 + (w>>4);
    int si = (((d&3)<<4) + (h&15))*16 + (w&15);
    size_t widx = ((size_t)(b*NWIN+wi)*CC + c)*SSS + si;
    float v=0.f;
    #pragma unroll
    for (int t=0;t<TT;t++){
        float xn = in[(size_t)t*TSTRIDE + e]*sc + sh;
        v = (v+xn)*0.5f;
        float s = (v>=VTH)?1.f:0.f;
        spk[(size_t)t*TSTRIDE + widx] = s;
        v *= (1.f - s);
    }
}

// ---------------- window attention + output LIF -> bf16 spike frags ----------
// spkb[tb = t*B+b][icg16][p8192][8] bf16 {0,1}
__global__ __launch_bounds__(256) void attn_lif(const float* __restrict__ qspk,
        const float* __restrict__ kspk, const float* __restrict__ vspk,
        const int* __restrict__ idx, ushortT* __restrict__ spkb) {
    int id = blockIdx.x*256 + threadIdx.x;   // B*W*H*S = 131072
    if (id >= BB*NWIN*NHEAD*SSS) return;
    int s  = id & 1023;
    int hh = (id>>10) & 7;
    int wi = (id>>13) & 7;
    int b  = id>>16;
    int bw = b*NWIN+wi;
    size_t qbase = ((size_t)bw*CC + hh*HDIM)*SSS + s;
    size_t sbase[4];
    #pragma unroll
    for (int j=0;j<4;j++){
        int src = idx[bw*4+j];
        sbase[j] = ((size_t)(b*NWIN+src)*CC + hh*HDIM)*SSS + s;
    }
    int wd = wi>>2, wh = (wi>>1)&1, ww = wi&1;
    int d3 = wd*4 + (s>>8), h3 = wh*16 + ((s>>4)&15), w3 = ww*16 + (s&15);
    int p  = (d3<<10) + (h3<<5) + w3;

    float v=0.f;
    float v2[16];
    #pragma unroll
    for (int dd=0; dd<16; dd++) v2[dd]=0.f;

    #pragma unroll 1
    for (int t=0;t<TT;t++){
        size_t toff = (size_t)t*TSTRIDE;
        float km[16], vm[16];
        #pragma unroll
        for (int dd=0;dd<16;dd++){ km[dd]=0.f; vm[dd]=0.f; }
        #pragma unroll
        for (int j=0;j<4;j++){
            const float* kp = kspk+toff+sbase[j];
            const float* vp = vspk+toff+sbase[j];
            #pragma unroll
            for (int dd=0; dd<16; dd++){
                km[dd] += kp[(size_t)dd*SSS];
                vm[dd] += vp[(size_t)dd*SSS];
            }
        }
        const float* qp = qspk+toff+qbase;
        float att=0.f;
        #pragma unroll
        for (int dd=0;dd<16;dd++) att += qp[(size_t)dd*SSS]*km[dd];
        att *= 0.25f;
        v = (v+att)*0.5f;
        float sp = (v>=VTH)?1.f:0.f;
        v *= (1.f-sp);
        float spq = sp*0.25f;
        union { ushortT u[8]; uint4 q4; } pk0, pk1;
        #pragma unroll
        for (int dd=0;dd<16;dd++){
            float ov = spq*vm[dd];
            v2[dd] = (v2[dd]+ov)*0.5f;
            float s2 = (v2[dd]>=VTH)?1.f:0.f;
            v2[dd] *= (1.f-s2);
            ushortT bs = (s2 != 0.f) ? (ushortT)0x3F80 : (ushortT)0;
            if (dd < 8) pk0.u[dd] = bs; else pk1.u[dd-8] = bs;
        }
        int tb2 = t*BB + b;
        size_t base = (((size_t)tb2*16 + hh*2)*PP + p)*8;
        *(uint4*)&spkb[base] = pk0.q4;
        *(uint4*)&spkb[base + (size_t)PP*8] = pk1.q4;
    }
}

// ---------------- p-stats: partials over (tb,c), then finalize ---------------
__global__ __launch_bounds__(256) void pstats_part(const float* __restrict__ xin,
        float* __restrict__ part_sum, float* __restrict__ part_sq) {
    int blk = blockIdx.x;                    // tb*128 + c
    int c = blk & 127, tb = blk >> 7;
    int tid = threadIdx.x;
    const float* p = xin + ((size_t)tb*CC + c)*PP;
    float s=0.f, s2=0.f;
    for (int i=tid; i<PP; i+=256){ float v=p[i]; s+=v; s2+=v*v; }
    __shared__ float ls[256], ls2[256];
    ls[tid]=s; ls2[tid]=s2; __syncthreads();
    for (int off=128; off>0; off>>=1){
        if (tid<off){ ls[tid]+=ls[tid+off]; ls2[tid]+=ls2[tid+off]; }
        __syncthreads();
    }
    if (tid==0){ part_sum[blk]=ls[0]; part_sq[blk]=ls2[0]; }
}

__global__ __launch_bounds__(128) void pstats_fin(const float* __restrict__ part_sum,
        const float* __restrict__ part_sq, float* __restrict__ sum,
        float* __restrict__ sq) {
    int c = threadIdx.x;
    float s=0.f, s2=0.f;
    for (int tb=0; tb<8; tb++){
        s  += part_sum[tb*128+c];
        s2 += part_sq[tb*128+c];
    }
    sum[c]=s; sq[c]=s2;
}

// ---------------- final BN apply ---------------------------------------------
__global__ __launch_bounds__(256) void bn_apply(const float* __restrict__ xin,
        float* __restrict__ yout,
        const float* __restrict__ sum, const float* __restrict__ sq,
        const float* __restrict__ gamma, const float* __restrict__ beta) {
    size_t i = (size_t)blockIdx.x*256 + threadIdx.x;
    if (i >= (size_t)TT*BB*CC*PP) return;
    int c = (int)((i>>13)&127);
    float mean = sum[c]*(1.f/NPERC);
    float var  = sq[c]*(1.f/NPERC) - mean*mean;
    float sc = rsqrtf(var+EPSf)*gamma[c];
    float sh = beta[c] - mean*sc;
    yout[i] = xin[i]*sc + sh;
}

extern "C" void kernel_launch(void* const* d_in, const int* in_sizes, int n_in,
                              void* d_out, int out_size, void* d_ws, size_t ws_size,
                              hipStream_t stream) {
    const float* x  = (const float*)d_in[0];
    const float* qw = (const float*)d_in[1];
    const float* qg = (const float*)d_in[2];
    const float* qb = (const float*)d_in[3];
    const float* kw = (const float*)d_in[4];
    const float* kg = (const float*)d_in[5];
    const float* kb = (const float*)d_in[6];
    const float* vg = (const float*)d_in[7];
    const float* vb = (const float*)d_in[8];
    const float* pw = (const float*)d_in[9];
    const float* pg = (const float*)d_in[10];
    const float* pb = (const float*)d_in[11];
    float* out = (float*)d_out;
    float* ws  = (float*)d_ws;

    const size_t NEL = (size_t)TT*TSTRIDE;   // 8,388,608 floats
    float* qconv = ws;                       // [0, NEL)
    float* kconv = ws + NEL;                 // [NEL, 2NEL)
    float* qspk  = ws + 2*NEL;
    float* kspk  = ws + 3*NEL;
    float* vspk  = ws + 4*NEL;
    float* wmodT = ws + 5*NEL;               // 442368 floats
    float* stats = ws + 5*NEL + 442368;
    float *qsum=stats,     *qsq=stats+128,  *ksum=stats+256, *ksq=stats+384,
          *psum=stats+768, *psq=stats+896;
    float* rsum = stats + 1024;              // 6144
    float* rsq  = rsum + 6144;               // 6144
    float* ppart_sum = rsq + 6144;           // 1024
    float* ppart_sq  = ppart_sum + 1024;     // 1024
    int*   idxp = (int*)(ppart_sq + 1024);   // 64 ints

    // lifetimes:
    //  xsp (56.8MB) overlays qspk+part of kspk until kgemm done (< 4NEL ✓)
    //  wfrag (2.65MB) + wkfrag (0.2MB) at vspk base; dead before lif writes vspk
    //  spkb (16.8MB bf16) at kconv base; written by attn after kconv consumed
    //  wpfrag rebuilt into vspk base AFTER attn (vspk dead), read by pgemm
    //  pconv at qspk region (xsp+qspk dead after attn)
    ushortT* xsp    = (ushortT*)(ws + 2*NEL);
    ushortT* wfrag  = (ushortT*)(ws + 4*NEL);
    ushortT* wkfrag = (ushortT*)(ws + 4*NEL) + 1327104;
    ushortT* wpfrag = (ushortT*)(ws + 4*NEL);
    ushortT* spkb   = (ushortT*)(ws + NEL);
    float*   pconv  = ws + 2*NEL;

    prep_wmodT<<<64,256,0,stream>>>(qw, wmodT);
    prep_wfrag<<<216,256,0,stream>>>(wmodT, wfrag);
    prep_w1frag<<<8,256,0,stream>>>(kw, wkfrag);
    build_xsplit<<<4624,256,0,stream>>>(x, xsp);
    {
        dim3 gg(8,8,8);
        conv_mfma<<<gg,256,0,stream>>>(xsp, wfrag, qconv);
        kgemm_mfma<<<gg,256,0,stream>>>(xsp, wkfrag, kconv);
    }
    win_stats<<<6144,128,0,stream>>>(qconv, kconv, x, rsum, rsq);
    stats_fin<<<1,384,0,stream>>>(rsum, rsq, stats);
    route_topk<<<1,128,0,stream>>>(rsum, rsum+2048, qsum,qsq,ksum,ksq,qg,qb,kg,kb,idxp);
    {
        dim3 lg(8192,3);
        lif_bn_win3<<<lg,256,0,stream>>>(qconv,kconv,x, qspk,kspk,vspk,
                                         stats, qg,qb,kg,kb,vg,vb);
    }
    attn_lif<<<512,256,0,stream>>>(qspk,kspk,vspk,idxp,spkb);
    prep_w1frag<<<8,256,0,stream>>>(pw, wpfrag);
    {
        dim3 gg(8,8,8);
        pgemm_mfma<<<gg,256,0,stream>>>(spkb, wpfrag, pconv);
    }
    pstats_part<<<1024,256,0,stream>>>(pconv, ppart_sum, ppart_sq);
    pstats_fin<<<1,128,0,stream>>>(ppart_sum, ppart_sq, psum, psq);
    bn_apply<<<32768,256,0,stream>>>(pconv, out, psum, psq, pg, pb);
}

// Round 8
// 531.467 us; speedup vs baseline: 2.0565x; 1.0206x over previous
//
#include <hip/hip_runtime.h>

#define TT 4
#define BB 2
#define CC 128
#define DD 8
#define HHH 32
#define WWW 32
#define PP (DD*HHH*WWW)        // 8192
#define TSTRIDE (BB*CC*PP)     // 2097152
#define NWIN 8
#define SSS 1024
#define NHEAD 8
#define HDIM 16
#define THETA 0.7f
#define VTH 1.0f
#define NPERC (TT*BB*PP)       // 65536
#define EPSf 1e-5f

typedef unsigned short ushortT;
typedef __bf16 bf16x8 __attribute__((ext_vector_type(8)));
typedef float  f32x16 __attribute__((ext_vector_type(16)));

__device__ __forceinline__ ushortT bf16rn(float x){
    unsigned u = __float_as_uint(x);
    unsigned r = (u + 0x7FFFu + ((u>>16)&1u)) >> 16;
    return (ushortT)r;
}
__device__ __forceinline__ float bf16tof(ushortT h){
    return __uint_as_float(((unsigned)h)<<16);
}

// ---------------- wmodT: fold CDC into center tap, layout [o][tap][ic] ------
__global__ __launch_bounds__(256) void prep_wmodT(const float* __restrict__ qw,
                                                  float* __restrict__ wmodT) {
    int oi = blockIdx.x*256 + threadIdx.x;
    if (oi >= CC*CC) return;
    int o  = oi >> 7;
    int ic = oi & 127;
    const float* wp = qw + (size_t)oi*27;
    float kd = 0.f;
    #pragma unroll
    for (int t=0; t<9; t++) kd += wp[t] + wp[18+t];
    #pragma unroll
    for (int t=0; t<27; t++) {
        float v = wp[t] - ((t==13) ? THETA*kd : 0.f);
        wmodT[((size_t)o*27 + t)*CC + ic] = v;
    }
}

// ---------------- conv a-frag split weights ---------------------------------
// wfrag[kb8][tap27][m4][split3][lane64][8]
__global__ __launch_bounds__(256) void prep_wfrag(const float* __restrict__ wmodT,
                                                  ushortT* __restrict__ wfrag) {
    int id = blockIdx.x*256 + threadIdx.x;   // 8*27*4*64 = 55296
    if (id >= 8*27*4*64) return;
    int lane = id & 63;
    int r = id >> 6;
    int m = r & 3; r >>= 2;
    int t = r % 27;
    int kb = r / 27;
    int o   = m*32 + (lane & 31);
    int ic0 = kb*16 + (lane>>5)*8;
    size_t base = ((size_t)(id>>6))*3*64*8 + (size_t)lane*8;
    #pragma unroll
    for (int j=0;j<8;j++){
        float v = wmodT[((size_t)o*27 + t)*CC + ic0 + j];
        ushortT hi = bf16rn(v);  float r1 = v - bf16tof(hi);
        ushortT mi = bf16rn(r1); float r2 = r1 - bf16tof(mi);
        ushortT lo = bf16rn(r2);
        wfrag[base + 0*64*8 + j] = hi;
        wfrag[base + 1*64*8 + j] = mi;
        wfrag[base + 2*64*8 + j] = lo;
    }
}

// ---------------- 1x1 weight split frags: frag[kb8][m4][sp3][lane64][8] -----
__global__ __launch_bounds__(256) void prep_w1frag(const float* __restrict__ W,
                                                   ushortT* __restrict__ frag) {
    int id = blockIdx.x*256 + threadIdx.x;   // 2048
    if (id >= 2048) return;
    int lane = id & 63;
    int r = id >> 6;
    int m = r & 3;
    int kb = r >> 2;
    int o   = m*32 + (lane & 31);
    int ic0 = kb*16 + (lane>>5)*8;
    size_t base = ((size_t)(kb*4+m))*3*64*8 + (size_t)lane*8;
    #pragma unroll
    for (int j=0;j<8;j++){
        float v = W[(size_t)o*CC + ic0 + j];
        ushortT hi = bf16rn(v);  float r1 = v - bf16tof(hi);
        ushortT mi = bf16rn(r1); float r2 = r1 - bf16tof(mi);
        ushortT lo = bf16rn(r2);
        frag[base + 0*64*8 + j] = hi;
        frag[base + 1*64*8 + j] = mi;
        frag[base + 2*64*8 + j] = lo;
    }
}

// ---------------- bf16-split padded x (h/w halos only, no d halo) -----------
// xsp[tb][sp3][icg16][d8][hp34][wt34][ic8]; hp/wt 0,33 are zero halos
__global__ __launch_bounds__(256) void build_xsplit(const float* __restrict__ x,
                                                    ushortT* __restrict__ xsp) {
    int id = blockIdx.x*256 + threadIdx.x;   // 8*16*8*34*34 = 1,183,744
    if (id >= 8*16*8*34*34) return;
    int wt = id % 34; int r = id/34;
    int hp = r % 34;  r /= 34;
    int dz = r % 8;   r /= 8;
    int icg = r & 15; int tb = r >> 4;
    bool inb = (hp>=1) & (hp<=32) & (wt>=1) & (wt<=32);
    ushortT h8[8], mm8[8], l8[8];
    #pragma unroll
    for (int j=0;j<8;j++){
        float v = 0.f;
        if (inb)
            v = x[((size_t)(tb*CC + icg*8+j))*PP + (size_t)dz*1024 + (hp-1)*32 + (wt-1)];
        ushortT hi = bf16rn(v);  float r1 = v - bf16tof(hi);
        ushortT mi = bf16rn(r1); float r2 = r1 - bf16tof(mi);
        ushortT lo = bf16rn(r2);
        h8[j]=hi; mm8[j]=mi; l8[j]=lo;
    }
    #pragma unroll
    for (int sp=0; sp<3; sp++){
        size_t gu = (((((size_t)tb*3 + sp)*16 + icg)*8 + dz)*34 + hp)*34 + wt;
        ushortT* dst = xsp + gu*8;
        const ushortT* src = (sp==0)?h8:((sp==1)?mm8:l8);
        #pragma unroll
        for (int j=0;j<8;j++) dst[j] = src[j];
    }
}

// ---------------- conv via 32x32x16 MFMA: 2 d-tiles/wave, kb-split ----------
// grid (hg8, dp4, tb8*kh2); block 256 = 4 waves = 4 h-rows; wave owns d0,d0+1.
__global__ __launch_bounds__(256,2) void conv_mfma2(const ushortT* __restrict__ xsp,
                                                    const ushortT* __restrict__ wfrag,
                                                    float* __restrict__ y0,
                                                    float* __restrict__ y1) {
    __shared__ ushortT slab[4896*8];         // 78.3 KB
    int tid  = threadIdx.x;
    int wid  = tid >> 6;
    int lane = tid & 63;
    int ln   = lane & 31;
    int half = lane >> 5;
    int hg = blockIdx.x;                     // 0..7
    int dp = blockIdx.y;                     // 0..3
    int z  = blockIdx.z;                     // 0..15
    int tb = z >> 1, kh = z & 1;
    int H0 = hg*4, d0 = dp*2;
    float* y = kh ? y1 : y0;

    f32x16 acc[2][4];
    #pragma unroll
    for (int dt=0;dt<2;dt++)
        #pragma unroll
        for (int m=0;m<4;m++)
            #pragma unroll
            for (int i=0;i<16;i++) acc[dt][m][i] = 0.f;

    // a-frag prefetch for (kb=kh*4, t=0)
    bf16x8 ca[4][3];
    #pragma unroll
    for (int m=0;m<4;m++)
        #pragma unroll
        for (int sp=0;sp<3;sp++)
            ca[m][sp] = *(const bf16x8*)&wfrag[((((size_t)(kh*4*27)*4)+(size_t)m*3+sp)*64 + lane)*8];

    #pragma unroll 1
    for (int kk=0; kk<4; kk++) {
        int kb = kh*4 + kk;
        __syncthreads();
        // stage slab: [sp3][icg2][dz4][hp6][wt34] units of 16B
        for (int u = tid; u < 4896; u += 256) {
            int sp  = u / 1632;
            int r   = u - sp*1632;
            int icg = r / 816;
            int p   = r - icg*816;
            int dz  = p / 204;
            int r3  = p - dz*204;
            int hp  = r3 / 34;
            int wt  = r3 - hp*34;
            int dd  = d0 - 1 + dz;
            ulonglong2 v; v.x = 0; v.y = 0;
            if ((unsigned)dd < 8u) {
                size_t gu = (((((size_t)tb*3 + sp)*16 + (kb*2+icg))*8 + dd)*34 + (H0+hp))*34 + wt;
                v = *(const ulonglong2*)&xsp[gu*8];
            }
            *(ulonglong2*)&slab[(size_t)u*8] = v;
        }
        __syncthreads();
        #pragma unroll 1
        for (int t=0; t<27; t++) {
            int dz=t/9; int rr=t-dz*9; int dh=rr/3; int dw=rr-dh*3;
            // b-frags fresh from LDS: 2 d-tiles x 3 splits
            bf16x8 cb[2][3];
            #pragma unroll
            for (int dt=0;dt<2;dt++){
                int bpos = (dt+dz)*204 + (wid+dh)*34 + ln + dw;
                #pragma unroll
                for (int sp=0;sp<3;sp++)
                    cb[dt][sp] = *(const bf16x8*)&slab[(size_t)((sp*2+half)*816 + bpos)*8];
            }
            // a-frag prefetch for next tap
            bf16x8 na[4][3];
            int nt  = (t<26)? t+1 : 0;
            int nkb = (t<26)? kb  : ((kk<3)? kb+1 : kb);
            #pragma unroll
            for (int m=0;m<4;m++)
                #pragma unroll
                for (int sp=0;sp<3;sp++)
                    na[m][sp] = *(const bf16x8*)&wfrag[((((size_t)(nkb*27+nt)*4+m)*3+sp)*64 + lane)*8];
            // 6 split terms; per term: dt, m (per-acc order = term order, as R7)
            #pragma unroll
            for (int dt=0;dt<2;dt++)
                #pragma unroll
                for (int m=0;m<4;m++) acc[dt][m] = __builtin_amdgcn_mfma_f32_32x32x16_bf16(ca[m][0], cb[dt][0], acc[dt][m],0,0,0);
            #pragma unroll
            for (int dt=0;dt<2;dt++)
                #pragma unroll
                for (int m=0;m<4;m++) acc[dt][m] = __builtin_amdgcn_mfma_f32_32x32x16_bf16(ca[m][0], cb[dt][1], acc[dt][m],0,0,0);
            #pragma unroll
            for (int dt=0;dt<2;dt++)
                #pragma unroll
                for (int m=0;m<4;m++) acc[dt][m] = __builtin_amdgcn_mfma_f32_32x32x16_bf16(ca[m][1], cb[dt][0], acc[dt][m],0,0,0);
            #pragma unroll
            for (int dt=0;dt<2;dt++)
                #pragma unroll
                for (int m=0;m<4;m++) acc[dt][m] = __builtin_amdgcn_mfma_f32_32x32x16_bf16(ca[m][0], cb[dt][2], acc[dt][m],0,0,0);
            #pragma unroll
            for (int dt=0;dt<2;dt++)
                #pragma unroll
                for (int m=0;m<4;m++) acc[dt][m] = __builtin_amdgcn_mfma_f32_32x32x16_bf16(ca[m][1], cb[dt][1], acc[dt][m],0,0,0);
            #pragma unroll
            for (int dt=0;dt<2;dt++)
                #pragma unroll
                for (int m=0;m<4;m++) acc[dt][m] = __builtin_amdgcn_mfma_f32_32x32x16_bf16(ca[m][2], cb[dt][0], acc[dt][m],0,0,0);
            #pragma unroll
            for (int m=0;m<4;m++)
                #pragma unroll
                for (int sp=0;sp<3;sp++) ca[m][sp] = na[m][sp];
        }
    }
    int h = H0 + wid;
    #pragma unroll
    for (int dt=0; dt<2; dt++) {
        #pragma unroll
        for (int m=0; m<4; m++) {
            #pragma unroll
            for (int reg=0; reg<16; reg++) {
                int row = (reg&3) + 8*(reg>>2) + 4*half;
                int o = m*32 + row;
                y[((size_t)tb*CC + o)*PP + (d0+dt)*1024 + h*32 + ln] = acc[dt][m][reg];
            }
        }
    }
}

// ---------------- sum the two kb-half partials -------------------------------
__global__ __launch_bounds__(256) void conv_add(float* __restrict__ q,
                                                const float* __restrict__ p1) {
    size_t i = ((size_t)blockIdx.x*256 + threadIdx.x)*4;
    float4 a = *(const float4*)&q[i];
    float4 b = *(const float4*)&p1[i];
    a.x+=b.x; a.y+=b.y; a.z+=b.z; a.w+=b.w;
    *(float4*)&q[i] = a;
}

// ---------------- k-gemm (1x1) via MFMA, 6-term split, reads xsp ------------
__global__ __launch_bounds__(256) void kgemm_mfma(const ushortT* __restrict__ xsp,
                                                  const ushortT* __restrict__ wk,
                                                  float* __restrict__ y) {
    int tid  = threadIdx.x;
    int wid  = tid >> 6;
    int lane = tid & 63;
    int ln   = lane & 31;
    int half = lane >> 5;
    int hg = blockIdx.x, d = blockIdx.y, tb = blockIdx.z;
    int h = hg*4 + wid;

    f32x16 acc[4];
    #pragma unroll
    for (int m=0;m<4;m++)
        #pragma unroll
        for (int i=0;i<16;i++) acc[m][i] = 0.f;

    #pragma unroll 2
    for (int kb=0; kb<8; kb++) {
        bf16x8 b[3];
        #pragma unroll
        for (int sp=0; sp<3; sp++) {
            size_t gu = (((((size_t)tb*3 + sp)*16 + (kb*2+half))*8 + d)*34 + (h+1))*34 + (ln+1);
            b[sp] = *(const bf16x8*)&xsp[gu*8];
        }
        #pragma unroll
        for (int m=0; m<4; m++) {
            const ushortT* wb = wk + ((size_t)(kb*4+m))*3*64*8 + (size_t)lane*8;
            bf16x8 a0 = *(const bf16x8*)&wb[0*64*8];
            bf16x8 a1 = *(const bf16x8*)&wb[1*64*8];
            bf16x8 a2 = *(const bf16x8*)&wb[2*64*8];
            acc[m] = __builtin_amdgcn_mfma_f32_32x32x16_bf16(a0, b[0], acc[m],0,0,0);
            acc[m] = __builtin_amdgcn_mfma_f32_32x32x16_bf16(a0, b[1], acc[m],0,0,0);
            acc[m] = __builtin_amdgcn_mfma_f32_32x32x16_bf16(a1, b[0], acc[m],0,0,0);
            acc[m] = __builtin_amdgcn_mfma_f32_32x32x16_bf16(a0, b[2], acc[m],0,0,0);
            acc[m] = __builtin_amdgcn_mfma_f32_32x32x16_bf16(a1, b[1], acc[m],0,0,0);
            acc[m] = __builtin_amdgcn_mfma_f32_32x32x16_bf16(a2, b[0], acc[m],0,0,0);
        }
    }
    #pragma unroll
    for (int m=0; m<4; m++) {
        #pragma unroll
        for (int reg=0; reg<16; reg++) {
            int row = (reg&3) + 8*(reg>>2) + 4*half;
            int o = m*32 + row;
            y[((size_t)tb*CC + o)*PP + d*1024 + h*32 + ln] = acc[m][reg];
        }
    }
}

// ---------------- p-gemm via MFMA: exact bf16 spikes x 3-split weights ------
__global__ __launch_bounds__(256) void pgemm_mfma(const ushortT* __restrict__ spkb,
                                                  const ushortT* __restrict__ wp,
                                                  float* __restrict__ y) {
    int tid  = threadIdx.x;
    int wid  = tid >> 6;
    int lane = tid & 63;
    int ln   = lane & 31;
    int half = lane >> 5;
    int hg = blockIdx.x, d = blockIdx.y, tb = blockIdx.z;
    int h = hg*4 + wid;
    int p = d*1024 + h*32 + ln;

    f32x16 acc[4];
    #pragma unroll
    for (int m=0;m<4;m++)
        #pragma unroll
        for (int i=0;i<16;i++) acc[m][i] = 0.f;

    #pragma unroll 2
    for (int kb=0; kb<8; kb++) {
        bf16x8 b = *(const bf16x8*)&spkb[(((size_t)tb*16 + (kb*2+half))*PP + p)*8];
        #pragma unroll
        for (int m=0; m<4; m++) {
            const ushortT* wb = wp + ((size_t)(kb*4+m))*3*64*8 + (size_t)lane*8;
            bf16x8 a0 = *(const bf16x8*)&wb[0*64*8];
            bf16x8 a1 = *(const bf16x8*)&wb[1*64*8];
            bf16x8 a2 = *(const bf16x8*)&wb[2*64*8];
            acc[m] = __builtin_amdgcn_mfma_f32_32x32x16_bf16(a0, b, acc[m],0,0,0);
            acc[m] = __builtin_amdgcn_mfma_f32_32x32x16_bf16(a1, b, acc[m],0,0,0);
            acc[m] = __builtin_amdgcn_mfma_f32_32x32x16_bf16(a2, b, acc[m],0,0,0);
        }
    }
    #pragma unroll
    for (int m=0; m<4; m++) {
        #pragma unroll
        for (int reg=0; reg<16; reg++) {
            int row = (reg&3) + 8*(reg>>2) + 4*half;
            int o = m*32 + row;
            y[((size_t)tb*CC + o)*PP + p] = acc[m][reg];
        }
    }
}

// ---------------- per-(src,b,win,c) sum & sumsq partials ---------------------
__global__ __launch_bounds__(128) void win_stats(const float* __restrict__ q,
        const float* __restrict__ k, const float* __restrict__ x,
        float* __restrict__ rsum, float* __restrict__ rsq) {
    int blk = blockIdx.x;
    int src = blk >> 11;
    int r   = blk & 2047;
    const float* base = (src==0) ? q : ((src==1) ? k : x);
    int c  = r & 127;
    int wi = (r >> 7) & 7;
    int b  = r >> 10;
    int wd = wi>>2, wh = (wi>>1)&1, ww = wi&1;
    int tid = threadIdx.x;
    float s=0.f, s2=0.f;
    for (int t=0;t<TT;t++){
        const float* p = base + ((size_t)(t*BB+b)*CC + c)*PP;
        for (int si=tid; si<SSS; si+=128){
            int ld = si>>8, lh=(si>>4)&15, lw=si&15;
            float v = p[((wd*4+ld)<<10) + ((wh*16+lh)<<5) + (ww*16+lw)];
            s += v; s2 += v*v;
        }
    }
    __shared__ float ls[128], ls2[128];
    ls[tid]=s; ls2[tid]=s2; __syncthreads();
    for (int off=64;off>0;off>>=1){
        if(tid<off){ ls[tid]+=ls[tid+off]; ls2[tid]+=ls2[tid+off]; }
        __syncthreads();
    }
    if (tid==0){ rsum[blk]=ls[0]; rsq[blk]=ls2[0]; }
}

// ---------------- finalize per-channel stats for q,k,v ----------------------
__global__ __launch_bounds__(384) void stats_fin(const float* __restrict__ rsum,
        const float* __restrict__ rsq, float* __restrict__ sums) {
    int tid = threadIdx.x;
    int src = tid >> 7, c = tid & 127;
    float s=0.f, s2=0.f;
    for (int bw=0; bw<16; bw++){
        int idx = src*2048 + bw*128 + c;
        s  += rsum[idx];
        s2 += rsq[idx];
    }
    sums[src*256 + c]       = s;
    sums[src*256 + 128 + c] = s2;
}

// ---------------- routing: normalize regions, a_r, top-4 --------------------
__global__ __launch_bounds__(128) void route_topk(const float* __restrict__ qreg,
        const float* __restrict__ kreg,
        const float* __restrict__ qsum, const float* __restrict__ qsq,
        const float* __restrict__ ksum, const float* __restrict__ ksq,
        const float* __restrict__ qg, const float* __restrict__ qb,
        const float* __restrict__ kg, const float* __restrict__ kb,
        int* __restrict__ idxout) {
    __shared__ float qn[16*128], kn[16*128], ar[16*8];
    int tid = threadIdx.x;
    for (int e=tid; e<16*128; e+=128){
        int c = e&127;
        float qm = qsum[c]*(1.f/NPERC);
        float qv = qsq[c]*(1.f/NPERC) - qm*qm;
        float qr = rsqrtf(qv + EPSf);
        qn[e] = (qreg[e]*(1.f/(TT*SSS)) - qm)*qr*qg[c] + qb[c];
        float km = ksum[c]*(1.f/NPERC);
        float kv = ksq[c]*(1.f/NPERC) - km*km;
        float kr = rsqrtf(kv + EPSf);
        kn[e] = (kreg[e]*(1.f/(TT*SSS)) - km)*kr*kg[c] + kb[c];
    }
    __syncthreads();
    {
        int b = tid>>6, w=(tid>>3)&7, v=tid&7;
        float s=0.f;
        for (int c=0;c<128;c++) s += qn[(b*8+w)*128+c]*kn[(b*8+v)*128+c];
        ar[(b*8+w)*8+v] = s * 0.25f;
    }
    __syncthreads();
    if (tid < 16){
        const float* row = &ar[tid*8];
        bool used[8] = {false,false,false,false,false,false,false,false};
        for (int j=0;j<4;j++){
            int best=0; float bv=-3.0e38f;
            for (int v=0; v<8; v++){
                if (!used[v] && row[v] > bv){ bv=row[v]; best=v; }
            }
            used[best]=true;
            idxout[tid*4+j]=best;
        }
    }
}

// ---------------- LIF+BN for q,k,v in ONE launch (grid.y = src) -------------
__global__ __launch_bounds__(256) void lif_bn_win3(const float* __restrict__ qin,
        const float* __restrict__ kin, const float* __restrict__ xin,
        float* __restrict__ qs, float* __restrict__ ks, float* __restrict__ vs,
        const float* __restrict__ stats,
        const float* __restrict__ qg, const float* __restrict__ qb,
        const float* __restrict__ kg, const float* __restrict__ kb,
        const float* __restrict__ vg, const float* __restrict__ vb) {
    int src = blockIdx.y;
    const float* in  = (src==0) ? qin : ((src==1) ? kin : xin);
    float*       spk = (src==0) ? qs  : ((src==1) ? ks  : vs);
    const float* gamma = (src==0) ? qg : ((src==1) ? kg : vg);
    const float* beta  = (src==0) ? qb : ((src==1) ? kb : vb);
    int e = blockIdx.x*256 + threadIdx.x;
    if (e >= BB*CC*PP) return;
    int p = e & (PP-1);
    int c = (e >> 13) & 127;
    int b = e >> 20;
    float mean = stats[src*256 + c]*(1.f/NPERC);
    float var  = stats[src*256 + 128 + c]*(1.f/NPERC) - mean*mean;
    float sc = rsqrtf(var+EPSf)*gamma[c];
    float sh = beta[c] - mean*sc;
    int d = p>>10, h=(p>>5)&31, w=p&31;
    int wi = ((d>>2)*2 + (h>>4))*2 + (w>>4);
    int si = (((d&3)<<4) + (h&15))*16 + (w&15);
    size_t widx = ((size_t)(b*NWIN+wi)*CC + c)*SSS + si;
    float v=0.f;
    #pragma unroll
    for (int t=0;t<TT;t++){
        float xn = in[(size_t)t*TSTRIDE + e]*sc + sh;
        v = (v+xn)*0.5f;
        float s = (v>=VTH)?1.f:0.f;
        spk[(size_t)t*TSTRIDE + widx] = s;
        v *= (1.f - s);
    }
}

// ---------------- window attention + output LIF -> bf16 spike frags ----------
// spkb[tb = t*B+b][icg16][p8192][8] bf16 {0,1}
__global__ __launch_bounds__(256) void attn_lif(const float* __restrict__ qspk,
        const float* __restrict__ kspk, const float* __restrict__ vspk,
        const int* __restrict__ idx, ushortT* __restrict__ spkb) {
    int id = blockIdx.x*256 + threadIdx.x;   // B*W*H*S = 131072
    if (id >= BB*NWIN*NHEAD*SSS) return;
    int s  = id & 1023;
    int hh = (id>>10) & 7;
    int wi = (id>>13) & 7;
    int b  = id>>16;
    int bw = b*NWIN+wi;
    size_t qbase = ((size_t)bw*CC + hh*HDIM)*SSS + s;
    size_t sbase[4];
    #pragma unroll
    for (int j=0;j<4;j++){
        int src = idx[bw*4+j];
        sbase[j] = ((size_t)(b*NWIN+src)*CC + hh*HDIM)*SSS + s;
    }
    int wd = wi>>2, wh = (wi>>1)&1, ww = wi&1;
    int d3 = wd*4 + (s>>8), h3 = wh*16 + ((s>>4)&15), w3 = ww*16 + (s&15);
    int p  = (d3<<10) + (h3<<5) + w3;

    float v=0.f;
    float v2[16];
    #pragma unroll
    for (int dd=0; dd<16; dd++) v2[dd]=0.f;

    #pragma unroll 1
    for (int t=0;t<TT;t++){
        size_t toff = (size_t)t*TSTRIDE;
        float km[16], vm[16];
        #pragma unroll
        for (int dd=0;dd<16;dd++){ km[dd]=0.f; vm[dd]=0.f; }
        #pragma unroll
        for (int j=0;j<4;j++){
            const float* kp = kspk+toff+sbase[j];
            const float* vp = vspk+toff+sbase[j];
            #pragma unroll
            for (int dd=0; dd<16; dd++){
                km[dd] += kp[(size_t)dd*SSS];
                vm[dd] += vp[(size_t)dd*SSS];
            }
        }
        const float* qp = qspk+toff+qbase;
        float att=0.f;
        #pragma unroll
        for (int dd=0;dd<16;dd++) att += qp[(size_t)dd*SSS]*km[dd];
        att *= 0.25f;
        v = (v+att)*0.5f;
        float sp = (v>=VTH)?1.f:0.f;
        v *= (1.f-sp);
        float spq = sp*0.25f;
        union { ushortT u[8]; uint4 q4; } pk0, pk1;
        #pragma unroll
        for (int dd=0;dd<16;dd++){
            float ov = spq*vm[dd];
            v2[dd] = (v2[dd]+ov)*0.5f;
            float s2 = (v2[dd]>=VTH)?1.f:0.f;
            v2[dd] *= (1.f-s2);
            ushortT bs = (s2 != 0.f) ? (ushortT)0x3F80 : (ushortT)0;
            if (dd < 8) pk0.u[dd] = bs; else pk1.u[dd-8] = bs;
        }
        int tb2 = t*BB + b;
        size_t base = (((size_t)tb2*16 + hh*2)*PP + p)*8;
        *(uint4*)&spkb[base] = pk0.q4;
        *(uint4*)&spkb[base + (size_t)PP*8] = pk1.q4;
    }
}

// ---------------- p-stats: partials over (tb,c), then finalize ---------------
__global__ __launch_bounds__(256) void pstats_part(const float* __restrict__ xin,
        float* __restrict__ part_sum, float* __restrict__ part_sq) {
    int blk = blockIdx.x;                    // tb*128 + c
    int c = blk & 127, tb = blk >> 7;
    int tid = threadIdx.x;
    const float* p = xin + ((size_t)tb*CC + c)*PP;
    float s=0.f, s2=0.f;
    for (int i=tid; i<PP; i+=256){ float v=p[i]; s+=v; s2+=v*v; }
    __shared__ float ls[256], ls2[256];
    ls[tid]=s; ls2[tid]=s2; __syncthreads();
    for (int off=128; off>0; off>>=1){
        if (tid<off){ ls[tid]+=ls[tid+off]; ls2[tid]+=ls2[tid+off]; }
        __syncthreads();
    }
    if (tid==0){ part_sum[blk]=ls[0]; part_sq[blk]=ls2[0]; }
}

__global__ __launch_bounds__(128) void pstats_fin(const float* __restrict__ part_sum,
        const float* __restrict__ part_sq, float* __restrict__ sum,
        float* __restrict__ sq) {
    int c = threadIdx.x;
    float s=0.f, s2=0.f;
    for (int tb=0; tb<8; tb++){
        s  += part_sum[tb*128+c];
        s2 += part_sq[tb*128+c];
    }
    sum[c]=s; sq[c]=s2;
}

// ---------------- final BN apply ---------------------------------------------
__global__ __launch_bounds__(256) void bn_apply(const float* __restrict__ xin,
        float* __restrict__ yout,
        const float* __restrict__ sum, const float* __restrict__ sq,
        const float* __restrict__ gamma, const float* __restrict__ beta) {
    size_t i = (size_t)blockIdx.x*256 + threadIdx.x;
    if (i >= (size_t)TT*BB*CC*PP) return;
    int c = (int)((i>>13)&127);
    float mean = sum[c]*(1.f/NPERC);
    float var  = sq[c]*(1.f/NPERC) - mean*mean;
    float sc = rsqrtf(var+EPSf)*gamma[c];
    float sh = beta[c] - mean*sc;
    yout[i] = xin[i]*sc + sh;
}

extern "C" void kernel_launch(void* const* d_in, const int* in_sizes, int n_in,
                              void* d_out, int out_size, void* d_ws, size_t ws_size,
                              hipStream_t stream) {
    const float* x  = (const float*)d_in[0];
    const float* qw = (const float*)d_in[1];
    const float* qg = (const float*)d_in[2];
    const float* qb = (const float*)d_in[3];
    const float* kw = (const float*)d_in[4];
    const float* kg = (const float*)d_in[5];
    const float* kb = (const float*)d_in[6];
    const float* vg = (const float*)d_in[7];
    const float* vb = (const float*)d_in[8];
    const float* pw = (const float*)d_in[9];
    const float* pg = (const float*)d_in[10];
    const float* pb = (const float*)d_in[11];
    float* out = (float*)d_out;
    float* ws  = (float*)d_ws;

    const size_t NEL = (size_t)TT*TSTRIDE;   // 8,388,608 floats
    float* qconv = ws;                       // [0, NEL)   = conv part0
    float* kconv = ws + NEL;                 // [NEL, 2NEL) = conv part1, then kconv
    float* qspk  = ws + 2*NEL;
    float* kspk  = ws + 3*NEL;
    float* vspk  = ws + 4*NEL;
    float* wmodT = ws + 5*NEL;               // 442368 floats
    float* stats = ws + 5*NEL + 442368;
    float *qsum=stats,     *qsq=stats+128,  *ksum=stats+256, *ksq=stats+384,
          *psum=stats+768, *psq=stats+896;
    float* rsum = stats + 1024;              // 6144
    float* rsq  = rsum + 6144;               // 6144
    float* ppart_sum = rsq + 6144;           // 1024
    float* ppart_sq  = ppart_sum + 1024;     // 1024
    int*   idxp = (int*)(ppart_sq + 1024);   // 64 ints

    // lifetimes:
    //  xsp (56.8MB) overlays qspk..(into kspk) until kgemm done
    //  wfrag (2.65MB) + wkfrag at vspk base; dead before lif writes vspk
    //  conv part1 in kconv region; conv_add consumes it BEFORE kgemm rewrites
    //  spkb (16.8MB) at kconv base; written by attn after kconv consumed
    //  wpfrag rebuilt into vspk base AFTER attn; pconv at qspk region
    ushortT* xsp    = (ushortT*)(ws + 2*NEL);
    ushortT* wfrag  = (ushortT*)(ws + 4*NEL);
    ushortT* wkfrag = (ushortT*)(ws + 4*NEL) + 1327104;
    ushortT* wpfrag = (ushortT*)(ws + 4*NEL);
    ushortT* spkb   = (ushortT*)(ws + NEL);
    float*   pconv  = ws + 2*NEL;
    float*   part1  = kconv;

    prep_wmodT<<<64,256,0,stream>>>(qw, wmodT);
    prep_wfrag<<<216,256,0,stream>>>(wmodT, wfrag);
    prep_w1frag<<<8,256,0,stream>>>(kw, wkfrag);
    build_xsplit<<<4624,256,0,stream>>>(x, xsp);
    {
        dim3 cg(8,4,16);
        conv_mfma2<<<cg,256,0,stream>>>(xsp, wfrag, qconv, part1);
    }
    conv_add<<<8192,256,0,stream>>>(qconv, part1);
    {
        dim3 gg(8,8,8);
        kgemm_mfma<<<gg,256,0,stream>>>(xsp, wkfrag, kconv);
    }
    win_stats<<<6144,128,0,stream>>>(qconv, kconv, x, rsum, rsq);
    stats_fin<<<1,384,0,stream>>>(rsum, rsq, stats);
    route_topk<<<1,128,0,stream>>>(rsum, rsum+2048, qsum,qsq,ksum,ksq,qg,qb,kg,kb,idxp);
    {
        dim3 lg(8192,3);
        lif_bn_win3<<<lg,256,0,stream>>>(qconv,kconv,x, qspk,kspk,vspk,
                                         stats, qg,qb,kg,kb,vg,vb);
    }
    attn_lif<<<512,256,0,stream>>>(qspk,kspk,vspk,idxp,spkb);
    prep_w1frag<<<8,256,0,stream>>>(pw, wpfrag);
    {
        dim3 gg(8,8,8);
        pgemm_mfma<<<gg,256,0,stream>>>(spkb, wpfrag, pconv);
    }
    pstats_part<<<1024,256,0,stream>>>(pconv, ppart_sum, ppart_sq);
    pstats_fin<<<1,128,0,stream>>>(ppart_sum, ppart_sq, psum, psq);
    bn_apply<<<32768,256,0,stream>>>(pconv, out, psum, psq, pg, pb);
}

// Round 9
// 449.593 us; speedup vs baseline: 2.4310x; 1.1821x over previous
//
#include <hip/hip_runtime.h>

#define TT 4
#define BB 2
#define CC 128
#define DD 8
#define HHH 32
#define WWW 32
#define PP (DD*HHH*WWW)        // 8192
#define TSTRIDE (BB*CC*PP)     // 2097152
#define NWIN 8
#define SSS 1024
#define NHEAD 8
#define HDIM 16
#define THETA 0.7f
#define VTH 1.0f
#define NPERC (TT*BB*PP)       // 65536
#define EPSf 1e-5f

typedef unsigned short ushortT;
typedef _Float16 half_t;
typedef _Float16 f16x8 __attribute__((ext_vector_type(8)));
typedef float    f32x16 __attribute__((ext_vector_type(16)));

// ---------------- wmodT: fold CDC into center tap, layout [o][tap][ic] ------
__global__ __launch_bounds__(256) void prep_wmodT(const float* __restrict__ qw,
                                                  float* __restrict__ wmodT) {
    int oi = blockIdx.x*256 + threadIdx.x;
    if (oi >= CC*CC) return;
    int o  = oi >> 7;
    int ic = oi & 127;
    const float* wp = qw + (size_t)oi*27;
    float kd = 0.f;
    #pragma unroll
    for (int t=0; t<9; t++) kd += wp[t] + wp[18+t];
    #pragma unroll
    for (int t=0; t<27; t++) {
        float v = wp[t] - ((t==13) ? THETA*kd : 0.f);
        wmodT[((size_t)o*27 + t)*CC + ic] = v;
    }
}

// ---------------- conv a-frag f16-split weights ------------------------------
// wfrag[kb8][tap27][m4][sp2][lane64][8]
__global__ __launch_bounds__(256) void prep_wfrag(const float* __restrict__ wmodT,
                                                  half_t* __restrict__ wfrag) {
    int id = blockIdx.x*256 + threadIdx.x;   // 55296
    if (id >= 8*27*4*64) return;
    int lane = id & 63;
    int r = id >> 6;
    int m = r & 3; r >>= 2;
    int t = r % 27;
    int kb = r / 27;
    int o   = m*32 + (lane & 31);
    int ic0 = kb*16 + (lane>>5)*8;
    size_t base = ((size_t)(id>>6))*2*64*8 + (size_t)lane*8;
    #pragma unroll
    for (int j=0;j<8;j++){
        float v = wmodT[((size_t)o*27 + t)*CC + ic0 + j];
        half_t h = (half_t)v;
        half_t l = (half_t)(v - (float)h);
        wfrag[base + 0*64*8 + j] = h;
        wfrag[base + 1*64*8 + j] = l;
    }
}

// ---------------- 1x1 weight f16 frags: frag[kb8][m4][sp2][lane64][8] -------
__global__ __launch_bounds__(256) void prep_w1frag(const float* __restrict__ W,
                                                   half_t* __restrict__ frag) {
    int id = blockIdx.x*256 + threadIdx.x;   // 2048
    if (id >= 2048) return;
    int lane = id & 63;
    int r = id >> 6;
    int m = r & 3;
    int kb = r >> 2;
    int o   = m*32 + (lane & 31);
    int ic0 = kb*16 + (lane>>5)*8;
    size_t base = ((size_t)(kb*4+m))*2*64*8 + (size_t)lane*8;
    #pragma unroll
    for (int j=0;j<8;j++){
        float v = W[(size_t)o*CC + ic0 + j];
        half_t h = (half_t)v;
        half_t l = (half_t)(v - (float)h);
        frag[base + 0*64*8 + j] = h;
        frag[base + 1*64*8 + j] = l;
    }
}

// ---------------- f16-split padded x (h/w halos only) ------------------------
// xsp[tb][sp2][icg16][d8][hp34][wt34][ic8]; hp/wt 0,33 zero halos
__global__ __launch_bounds__(256) void build_xsplit(const float* __restrict__ x,
                                                    half_t* __restrict__ xsp) {
    int id = blockIdx.x*256 + threadIdx.x;   // 8*16*8*34*34 = 1,183,744
    if (id >= 8*16*8*34*34) return;
    int wt = id % 34; int r = id/34;
    int hp = r % 34;  r /= 34;
    int dz = r % 8;   r /= 8;
    int icg = r & 15; int tb = r >> 4;
    bool inb = (hp>=1) & (hp<=32) & (wt>=1) & (wt<=32);
    half_t h8[8], l8[8];
    #pragma unroll
    for (int j=0;j<8;j++){
        float v = 0.f;
        if (inb)
            v = x[((size_t)(tb*CC + icg*8+j))*PP + (size_t)dz*1024 + (hp-1)*32 + (wt-1)];
        half_t h = (half_t)v;
        half_t l = (half_t)(v - (float)h);
        h8[j]=h; l8[j]=l;
    }
    #pragma unroll
    for (int sp=0; sp<2; sp++){
        size_t gu = (((((size_t)tb*2 + sp)*16 + icg)*8 + dz)*34 + hp)*34 + wt;
        half_t* dst = xsp + gu*8;
        const half_t* src = (sp==0)?h8:l8;
        #pragma unroll
        for (int j=0;j<8;j++) dst[j] = src[j];
    }
}

// ---------------- conv via 32x32x16 f16 MFMA: 2 d-tiles/wave, kb-split ------
// grid (hg8, dp4, tb8*kh2); block 256 = 4 waves = 4 h-rows; wave owns d0,d0+1.
__global__ __launch_bounds__(256,2) void conv_mfma2(const half_t* __restrict__ xsp,
                                                    const half_t* __restrict__ wfrag,
                                                    float* __restrict__ y0,
                                                    float* __restrict__ y1) {
    __shared__ half_t slab[3264*8];          // 52.2 KB
    int tid  = threadIdx.x;
    int wid  = tid >> 6;
    int lane = tid & 63;
    int ln   = lane & 31;
    int half_ = lane >> 5;
    int hg = blockIdx.x;                     // 0..7
    int dp = blockIdx.y;                     // 0..3
    int z  = blockIdx.z;                     // 0..15
    int tb = z >> 1, kh = z & 1;
    int H0 = hg*4, d0 = dp*2;
    float* y = kh ? y1 : y0;

    f32x16 acc[2][4];
    #pragma unroll
    for (int dt=0;dt<2;dt++)
        #pragma unroll
        for (int m=0;m<4;m++)
            #pragma unroll
            for (int i=0;i<16;i++) acc[dt][m][i] = 0.f;

    // a-frag prefetch for (kb=kh*4, t=0)
    f16x8 ca[4][2];
    #pragma unroll
    for (int m=0;m<4;m++)
        #pragma unroll
        for (int sp=0;sp<2;sp++)
            ca[m][sp] = *(const f16x8*)&wfrag[((((size_t)(kh*4*27)*4 + m)*2+sp)*64 + lane)*8];

    #pragma unroll 1
    for (int kk=0; kk<4; kk++) {
        int kb = kh*4 + kk;
        __syncthreads();
        // stage slab: [sp2][icg2][dz4][hp6][wt34] units of 16B
        for (int u = tid; u < 3264; u += 256) {
            int sp  = u / 1632;
            int r   = u - sp*1632;
            int icg = r / 816;
            int p   = r - icg*816;
            int dz  = p / 204;
            int r3  = p - dz*204;
            int hp  = r3 / 34;
            int wt  = r3 - hp*34;
            int dd  = d0 - 1 + dz;
            ulonglong2 v; v.x = 0; v.y = 0;
            if ((unsigned)dd < 8u) {
                size_t gu = (((((size_t)tb*2 + sp)*16 + (kb*2+icg))*8 + dd)*34 + (H0+hp))*34 + wt;
                v = *(const ulonglong2*)&xsp[gu*8];
            }
            *(ulonglong2*)&slab[(size_t)u*8] = v;
        }
        __syncthreads();
        #pragma unroll 1
        for (int t=0; t<27; t++) {
            int dz=t/9; int rr=t-dz*9; int dh=rr/3; int dw=rr-dh*3;
            // b-frags fresh from LDS: 2 d-tiles x 2 splits
            f16x8 cb[2][2];
            #pragma unroll
            for (int dt=0;dt<2;dt++){
                int bpos = (dt+dz)*204 + (wid+dh)*34 + ln + dw;
                #pragma unroll
                for (int sp=0;sp<2;sp++)
                    cb[dt][sp] = *(const f16x8*)&slab[(size_t)((sp*2+half_)*816 + bpos)*8];
            }
            // a-frag prefetch for next tap
            f16x8 na[4][2];
            int nt  = (t<26)? t+1 : 0;
            int nkb = (t<26)? kb  : ((kk<3)? kb+1 : kb);
            #pragma unroll
            for (int m=0;m<4;m++)
                #pragma unroll
                for (int sp=0;sp<2;sp++)
                    na[m][sp] = *(const f16x8*)&wfrag[((((size_t)(nkb*27+nt)*4+m)*2+sp)*64 + lane)*8];
            // 4 split terms: hh, hl, lh, ll
            #pragma unroll
            for (int dt=0;dt<2;dt++)
                #pragma unroll
                for (int m=0;m<4;m++) acc[dt][m] = __builtin_amdgcn_mfma_f32_32x32x16_f16(ca[m][0], cb[dt][0], acc[dt][m],0,0,0);
            #pragma unroll
            for (int dt=0;dt<2;dt++)
                #pragma unroll
                for (int m=0;m<4;m++) acc[dt][m] = __builtin_amdgcn_mfma_f32_32x32x16_f16(ca[m][0], cb[dt][1], acc[dt][m],0,0,0);
            #pragma unroll
            for (int dt=0;dt<2;dt++)
                #pragma unroll
                for (int m=0;m<4;m++) acc[dt][m] = __builtin_amdgcn_mfma_f32_32x32x16_f16(ca[m][1], cb[dt][0], acc[dt][m],0,0,0);
            #pragma unroll
            for (int dt=0;dt<2;dt++)
                #pragma unroll
                for (int m=0;m<4;m++) acc[dt][m] = __builtin_amdgcn_mfma_f32_32x32x16_f16(ca[m][1], cb[dt][1], acc[dt][m],0,0,0);
            #pragma unroll
            for (int m=0;m<4;m++)
                #pragma unroll
                for (int sp=0;sp<2;sp++) ca[m][sp] = na[m][sp];
        }
    }
    int h = H0 + wid;
    #pragma unroll
    for (int dt=0; dt<2; dt++) {
        #pragma unroll
        for (int m=0; m<4; m++) {
            #pragma unroll
            for (int reg=0; reg<16; reg++) {
                int row = (reg&3) + 8*(reg>>2) + 4*half_;
                int o = m*32 + row;
                y[((size_t)tb*CC + o)*PP + (d0+dt)*1024 + h*32 + ln] = acc[dt][m][reg];
            }
        }
    }
}

// ---------------- sum the two kb-half partials -------------------------------
__global__ __launch_bounds__(256) void conv_add(float* __restrict__ q,
                                                const float* __restrict__ p1) {
    size_t i = ((size_t)blockIdx.x*256 + threadIdx.x)*4;
    float4 a = *(const float4*)&q[i];
    float4 b = *(const float4*)&p1[i];
    a.x+=b.x; a.y+=b.y; a.z+=b.z; a.w+=b.w;
    *(float4*)&q[i] = a;
}

// ---------------- k-gemm (1x1) via f16 MFMA, 4-term split, reads xsp --------
__global__ __launch_bounds__(256) void kgemm_mfma(const half_t* __restrict__ xsp,
                                                  const half_t* __restrict__ wk,
                                                  float* __restrict__ y) {
    int tid  = threadIdx.x;
    int wid  = tid >> 6;
    int lane = tid & 63;
    int ln   = lane & 31;
    int half_ = lane >> 5;
    int hg = blockIdx.x, d = blockIdx.y, tb = blockIdx.z;
    int h = hg*4 + wid;

    f32x16 acc[4];
    #pragma unroll
    for (int m=0;m<4;m++)
        #pragma unroll
        for (int i=0;i<16;i++) acc[m][i] = 0.f;

    #pragma unroll 2
    for (int kb=0; kb<8; kb++) {
        f16x8 b[2];
        #pragma unroll
        for (int sp=0; sp<2; sp++) {
            size_t gu = (((((size_t)tb*2 + sp)*16 + (kb*2+half_))*8 + d)*34 + (h+1))*34 + (ln+1);
            b[sp] = *(const f16x8*)&xsp[gu*8];
        }
        #pragma unroll
        for (int m=0; m<4; m++) {
            const half_t* wb = wk + ((size_t)(kb*4+m))*2*64*8 + (size_t)lane*8;
            f16x8 a0 = *(const f16x8*)&wb[0*64*8];
            f16x8 a1 = *(const f16x8*)&wb[1*64*8];
            acc[m] = __builtin_amdgcn_mfma_f32_32x32x16_f16(a0, b[0], acc[m],0,0,0);
            acc[m] = __builtin_amdgcn_mfma_f32_32x32x16_f16(a0, b[1], acc[m],0,0,0);
            acc[m] = __builtin_amdgcn_mfma_f32_32x32x16_f16(a1, b[0], acc[m],0,0,0);
            acc[m] = __builtin_amdgcn_mfma_f32_32x32x16_f16(a1, b[1], acc[m],0,0,0);
        }
    }
    #pragma unroll
    for (int m=0; m<4; m++) {
        #pragma unroll
        for (int reg=0; reg<16; reg++) {
            int row = (reg&3) + 8*(reg>>2) + 4*half_;
            int o = m*32 + row;
            y[((size_t)tb*CC + o)*PP + d*1024 + h*32 + ln] = acc[m][reg];
        }
    }
}

// ---------------- p-gemm via f16 MFMA: exact f16 spikes x 2-split weights ---
__global__ __launch_bounds__(256) void pgemm_mfma(const ushortT* __restrict__ spkb,
                                                  const half_t* __restrict__ wp,
                                                  float* __restrict__ y) {
    int tid  = threadIdx.x;
    int wid  = tid >> 6;
    int lane = tid & 63;
    int ln   = lane & 31;
    int half_ = lane >> 5;
    int hg = blockIdx.x, d = blockIdx.y, tb = blockIdx.z;
    int h = hg*4 + wid;
    int p = d*1024 + h*32 + ln;

    f32x16 acc[4];
    #pragma unroll
    for (int m=0;m<4;m++)
        #pragma unroll
        for (int i=0;i<16;i++) acc[m][i] = 0.f;

    #pragma unroll 2
    for (int kb=0; kb<8; kb++) {
        f16x8 b = *(const f16x8*)&spkb[(((size_t)tb*16 + (kb*2+half_))*PP + p)*8];
        #pragma unroll
        for (int m=0; m<4; m++) {
            const half_t* wb = wp + ((size_t)(kb*4+m))*2*64*8 + (size_t)lane*8;
            f16x8 a0 = *(const f16x8*)&wb[0*64*8];
            f16x8 a1 = *(const f16x8*)&wb[1*64*8];
            acc[m] = __builtin_amdgcn_mfma_f32_32x32x16_f16(a0, b, acc[m],0,0,0);
            acc[m] = __builtin_amdgcn_mfma_f32_32x32x16_f16(a1, b, acc[m],0,0,0);
        }
    }
    #pragma unroll
    for (int m=0; m<4; m++) {
        #pragma unroll
        for (int reg=0; reg<16; reg++) {
            int row = (reg&3) + 8*(reg>>2) + 4*half_;
            int o = m*32 + row;
            y[((size_t)tb*CC + o)*PP + p] = acc[m][reg];
        }
    }
}

// ---------------- per-(src,b,win,c) sum & sumsq partials ---------------------
__global__ __launch_bounds__(128) void win_stats(const float* __restrict__ q,
        const float* __restrict__ k, const float* __restrict__ x,
        float* __restrict__ rsum, float* __restrict__ rsq) {
    int blk = blockIdx.x;
    int src = blk >> 11;
    int r   = blk & 2047;
    const float* base = (src==0) ? q : ((src==1) ? k : x);
    int c  = r & 127;
    int wi = (r >> 7) & 7;
    int b  = r >> 10;
    int wd = wi>>2, wh = (wi>>1)&1, ww = wi&1;
    int tid = threadIdx.x;
    float s=0.f, s2=0.f;
    for (int t=0;t<TT;t++){
        const float* p = base + ((size_t)(t*BB+b)*CC + c)*PP;
        for (int si=tid; si<SSS; si+=128){
            int ld = si>>8, lh=(si>>4)&15, lw=si&15;
            float v = p[((wd*4+ld)<<10) + ((wh*16+lh)<<5) + (ww*16+lw)];
            s += v; s2 += v*v;
        }
    }
    __shared__ float ls[128], ls2[128];
    ls[tid]=s; ls2[tid]=s2; __syncthreads();
    for (int off=64;off>0;off>>=1){
        if(tid<off){ ls[tid]+=ls[tid+off]; ls2[tid]+=ls2[tid+off]; }
        __syncthreads();
    }
    if (tid==0){ rsum[blk]=ls[0]; rsq[blk]=ls2[0]; }
}

// ---------------- finalize per-channel stats for q,k,v ----------------------
__global__ __launch_bounds__(384) void stats_fin(const float* __restrict__ rsum,
        const float* __restrict__ rsq, float* __restrict__ sums) {
    int tid = threadIdx.x;
    int src = tid >> 7, c = tid & 127;
    float s=0.f, s2=0.f;
    for (int bw=0; bw<16; bw++){
        int idx = src*2048 + bw*128 + c;
        s  += rsum[idx];
        s2 += rsq[idx];
    }
    sums[src*256 + c]       = s;
    sums[src*256 + 128 + c] = s2;
}

// ---------------- routing: normalize regions, a_r, top-4 --------------------
__global__ __launch_bounds__(128) void route_topk(const float* __restrict__ qreg,
        const float* __restrict__ kreg,
        const float* __restrict__ qsum, const float* __restrict__ qsq,
        const float* __restrict__ ksum, const float* __restrict__ ksq,
        const float* __restrict__ qg, const float* __restrict__ qb,
        const float* __restrict__ kg, const float* __restrict__ kb,
        int* __restrict__ idxout) {
    __shared__ float qn[16*128], kn[16*128], ar[16*8];
    int tid = threadIdx.x;
    for (int e=tid; e<16*128; e+=128){
        int c = e&127;
        float qm = qsum[c]*(1.f/NPERC);
        float qv = qsq[c]*(1.f/NPERC) - qm*qm;
        float qr = rsqrtf(qv + EPSf);
        qn[e] = (qreg[e]*(1.f/(TT*SSS)) - qm)*qr*qg[c] + qb[c];
        float km = ksum[c]*(1.f/NPERC);
        float kv = ksq[c]*(1.f/NPERC) - km*km;
        float kr = rsqrtf(kv + EPSf);
        kn[e] = (kreg[e]*(1.f/(TT*SSS)) - km)*kr*kg[c] + kb[c];
    }
    __syncthreads();
    {
        int b = tid>>6, w=(tid>>3)&7, v=tid&7;
        float s=0.f;
        for (int c=0;c<128;c++) s += qn[(b*8+w)*128+c]*kn[(b*8+v)*128+c];
        ar[(b*8+w)*8+v] = s * 0.25f;
    }
    __syncthreads();
    if (tid < 16){
        const float* row = &ar[tid*8];
        bool used[8] = {false,false,false,false,false,false,false,false};
        for (int j=0;j<4;j++){
            int best=0; float bv=-3.0e38f;
            for (int v=0; v<8; v++){
                if (!used[v] && row[v] > bv){ bv=row[v]; best=v; }
            }
            used[best]=true;
            idxout[tid*4+j]=best;
        }
    }
}

// ---------------- LIF+BN for q,k,v in ONE launch (grid.y = src) -------------
__global__ __launch_bounds__(256) void lif_bn_win3(const float* __restrict__ qin,
        const float* __restrict__ kin, const float* __restrict__ xin,
        float* __restrict__ qs, float* __restrict__ ks, float* __restrict__ vs,
        const float* __restrict__ stats,
        const float* __restrict__ qg, const float* __restrict__ qb,
        const float* __restrict__ kg, const float* __restrict__ kb,
        const float* __restrict__ vg, const float* __restrict__ vb) {
    int src = blockIdx.y;
    const float* in  = (src==0) ? qin : ((src==1) ? kin : xin);
    float*       spk = (src==0) ? qs  : ((src==1) ? ks  : vs);
    const float* gamma = (src==0) ? qg : ((src==1) ? kg : vg);
    const float* beta  = (src==0) ? qb : ((src==1) ? kb : vb);
    int e = blockIdx.x*256 + threadIdx.x;
    if (e >= BB*CC*PP) return;
    int p = e & (PP-1);
    int c = (e >> 13) & 127;
    int b = e >> 20;
    float mean = stats[src*256 + c]*(1.f/NPERC);
    float var  = stats[src*256 + 128 + c]*(1.f/NPERC) - mean*mean;
    float sc = rsqrtf(var+EPSf)*gamma[c];
    float sh = beta[c] - mean*sc;
    int d = p>>10, h=(p>>5)&31, w=p&31;
    int wi = ((d>>2)*2 + (h>>4))*2 + (w>>4);
    int si = (((d&3)<<4) + (h&15))*16 + (w&15);
    size_t widx = ((size_t)(b*NWIN+wi)*CC + c)*SSS + si;
    float v=0.f;
    #pragma unroll
    for (int t=0;t<TT;t++){
        float xn = in[(size_t)t*TSTRIDE + e]*sc + sh;
        v = (v+xn)*0.5f;
        float s = (v>=VTH)?1.f:0.f;
        spk[(size_t)t*TSTRIDE + widx] = s;
        v *= (1.f - s);
    }
}

// ---------------- window attention + output LIF -> f16 spike frags ----------
// spkb[tb = t*B+b][icg16][p8192][8] f16 {0,1}
__global__ __launch_bounds__(256) void attn_lif(const float* __restrict__ qspk,
        const float* __restrict__ kspk, const float* __restrict__ vspk,
        const int* __restrict__ idx, ushortT* __restrict__ spkb) {
    int id = blockIdx.x*256 + threadIdx.x;   // B*W*H*S = 131072
    if (id >= BB*NWIN*NHEAD*SSS) return;
    int s  = id & 1023;
    int hh = (id>>10) & 7;
    int wi = (id>>13) & 7;
    int b  = id>>16;
    int bw = b*NWIN+wi;
    size_t qbase = ((size_t)bw*CC + hh*HDIM)*SSS + s;
    size_t sbase[4];
    #pragma unroll
    for (int j=0;j<4;j++){
        int src = idx[bw*4+j];
        sbase[j] = ((size_t)(b*NWIN+src)*CC + hh*HDIM)*SSS + s;
    }
    int wd = wi>>2, wh = (wi>>1)&1, ww = wi&1;
    int d3 = wd*4 + (s>>8), h3 = wh*16 + ((s>>4)&15), w3 = ww*16 + (s&15);
    int p  = (d3<<10) + (h3<<5) + w3;

    float v=0.f;
    float v2[16];
    #pragma unroll
    for (int dd=0; dd<16; dd++) v2[dd]=0.f;

    #pragma unroll 1
    for (int t=0;t<TT;t++){
        size_t toff = (size_t)t*TSTRIDE;
        float km[16], vm[16];
        #pragma unroll
        for (int dd=0;dd<16;dd++){ km[dd]=0.f; vm[dd]=0.f; }
        #pragma unroll
        for (int j=0;j<4;j++){
            const float* kp = kspk+toff+sbase[j];
            const float* vp = vspk+toff+sbase[j];
            #pragma unroll
            for (int dd=0; dd<16; dd++){
                km[dd] += kp[(size_t)dd*SSS];
                vm[dd] += vp[(size_t)dd*SSS];
            }
        }
        const float* qp = qspk+toff+qbase;
        float att=0.f;
        #pragma unroll
        for (int dd=0;dd<16;dd++) att += qp[(size_t)dd*SSS]*km[dd];
        att *= 0.25f;
        v = (v+att)*0.5f;
        float sp = (v>=VTH)?1.f:0.f;
        v *= (1.f-sp);
        float spq = sp*0.25f;
        union { ushortT u[8]; uint4 q4; } pk0, pk1;
        #pragma unroll
        for (int dd=0;dd<16;dd++){
            float ov = spq*vm[dd];
            v2[dd] = (v2[dd]+ov)*0.5f;
            float s2 = (v2[dd]>=VTH)?1.f:0.f;
            v2[dd] *= (1.f-s2);
            ushortT bs = (s2 != 0.f) ? (ushortT)0x3C00 : (ushortT)0;   // f16 1.0
            if (dd < 8) pk0.u[dd] = bs; else pk1.u[dd-8] = bs;
        }
        int tb2 = t*BB + b;
        size_t base = (((size_t)tb2*16 + hh*2)*PP + p)*8;
        *(uint4*)&spkb[base] = pk0.q4;
        *(uint4*)&spkb[base + (size_t)PP*8] = pk1.q4;
    }
}

// ---------------- p-stats: partials over (tb,c), then finalize ---------------
__global__ __launch_bounds__(256) void pstats_part(const float* __restrict__ xin,
        float* __restrict__ part_sum, float* __restrict__ part_sq) {
    int blk = blockIdx.x;                    // tb*128 + c
    int c = blk & 127, tb = blk >> 7;
    int tid = threadIdx.x;
    const float* p = xin + ((size_t)tb*CC + c)*PP;
    float s=0.f, s2=0.f;
    for (int i=tid; i<PP; i+=256){ float v=p[i]; s+=v; s2+=v*v; }
    __shared__ float ls[256], ls2[256];
    ls[tid]=s; ls2[tid]=s2; __syncthreads();
    for (int off=128; off>0; off>>=1){
        if (tid<off){ ls[tid]+=ls[tid+off]; ls2[tid]+=ls2[tid+off]; }
        __syncthreads();
    }
    if (tid==0){ part_sum[blk]=ls[0]; part_sq[blk]=ls2[0]; }
}

__global__ __launch_bounds__(128) void pstats_fin(const float* __restrict__ part_sum,
        const float* __restrict__ part_sq, float* __restrict__ sum,
        float* __restrict__ sq) {
    int c = threadIdx.x;
    float s=0.f, s2=0.f;
    for (int tb=0; tb<8; tb++){
        s  += part_sum[tb*128+c];
        s2 += part_sq[tb*128+c];
    }
    sum[c]=s; sq[c]=s2;
}

// ---------------- final BN apply ---------------------------------------------
__global__ __launch_bounds__(256) void bn_apply(const float* __restrict__ xin,
        float* __restrict__ yout,
        const float* __restrict__ sum, const float* __restrict__ sq,
        const float* __restrict__ gamma, const float* __restrict__ beta) {
    size_t i = (size_t)blockIdx.x*256 + threadIdx.x;
    if (i >= (size_t)TT*BB*CC*PP) return;
    int c = (int)((i>>13)&127);
    float mean = sum[c]*(1.f/NPERC);
    float var  = sq[c]*(1.f/NPERC) - mean*mean;
    float sc = rsqrtf(var+EPSf)*gamma[c];
    float sh = beta[c] - mean*sc;
    yout[i] = xin[i]*sc + sh;
}

extern "C" void kernel_launch(void* const* d_in, const int* in_sizes, int n_in,
                              void* d_out, int out_size, void* d_ws, size_t ws_size,
                              hipStream_t stream) {
    const float* x  = (const float*)d_in[0];
    const float* qw = (const float*)d_in[1];
    const float* qg = (const float*)d_in[2];
    const float* qb = (const float*)d_in[3];
    const float* kw = (const float*)d_in[4];
    const float* kg = (const float*)d_in[5];
    const float* kb = (const float*)d_in[6];
    const float* vg = (const float*)d_in[7];
    const float* vb = (const float*)d_in[8];
    const float* pw = (const float*)d_in[9];
    const float* pg = (const float*)d_in[10];
    const float* pb = (const float*)d_in[11];
    float* out = (float*)d_out;
    float* ws  = (float*)d_ws;

    const size_t NEL = (size_t)TT*TSTRIDE;   // 8,388,608 floats
    float* qconv = ws;                       // conv part0
    float* kconv = ws + NEL;                 // conv part1, then kconv
    float* qspk  = ws + 2*NEL;
    float* kspk  = ws + 3*NEL;
    float* vspk  = ws + 4*NEL;
    float* wmodT = ws + 5*NEL;               // 442368 floats
    float* stats = ws + 5*NEL + 442368;
    float *qsum=stats,     *qsq=stats+128,  *ksum=stats+256, *ksq=stats+384,
          *psum=stats+768, *psq=stats+896;
    float* rsum = stats + 1024;              // 6144
    float* rsq  = rsum + 6144;               // 6144
    float* ppart_sum = rsq + 6144;           // 1024
    float* ppart_sq  = ppart_sum + 1024;     // 1024
    int*   idxp = (int*)(ppart_sq + 1024);   // 64 ints

    // lifetimes:
    //  xsp f16 (37.8MB) overlays qspk..(into kspk) until kgemm done
    //  wfrag f16 (1.77MB) + wkfrag at vspk base; dead before lif writes vspk
    //  conv part1 in kconv region; conv_add consumes it BEFORE kgemm rewrites
    //  spkb f16 (16.8MB) at kconv base; written by attn after kconv consumed
    //  wpfrag rebuilt into vspk base AFTER attn; pconv at qspk region
    half_t* xsp    = (half_t*)(ws + 2*NEL);
    half_t* wfrag  = (half_t*)(ws + 4*NEL);
    half_t* wkfrag = (half_t*)(ws + 4*NEL) + 884736;
    half_t* wpfrag = (half_t*)(ws + 4*NEL);
    ushortT* spkb  = (ushortT*)(ws + NEL);
    float*   pconv = ws + 2*NEL;
    float*   part1 = kconv;

    prep_wmodT<<<64,256,0,stream>>>(qw, wmodT);
    prep_wfrag<<<216,256,0,stream>>>(wmodT, wfrag);
    prep_w1frag<<<8,256,0,stream>>>(kw, wkfrag);
    build_xsplit<<<4624,256,0,stream>>>(x, xsp);
    {
        dim3 cg(8,4,16);
        conv_mfma2<<<cg,256,0,stream>>>(xsp, wfrag, qconv, part1);
    }
    conv_add<<<8192,256,0,stream>>>(qconv, part1);
    {
        dim3 gg(8,8,8);
        kgemm_mfma<<<gg,256,0,stream>>>(xsp, wkfrag, kconv);
    }
    win_stats<<<6144,128,0,stream>>>(qconv, kconv, x, rsum, rsq);
    stats_fin<<<1,384,0,stream>>>(rsum, rsq, stats);
    route_topk<<<1,128,0,stream>>>(rsum, rsum+2048, qsum,qsq,ksum,ksq,qg,qb,kg,kb,idxp);
    {
        dim3 lg(8192,3);
        lif_bn_win3<<<lg,256,0,stream>>>(qconv,kconv,x, qspk,kspk,vspk,
                                         stats, qg,qb,kg,kb,vg,vb);
    }
    attn_lif<<<512,256,0,stream>>>(qspk,kspk,vspk,idxp,spkb);
    prep_w1frag<<<8,256,0,stream>>>(pw, wpfrag);
    {
        dim3 gg(8,8,8);
        pgemm_mfma<<<gg,256,0,stream>>>(spkb, wpfrag, pconv);
    }
    pstats_part<<<1024,256,0,stream>>>(pconv, ppart_sum, ppart_sq);
    pstats_fin<<<1,128,0,stream>>>(ppart_sum, ppart_sq, psum, psq);
    bn_apply<<<32768,256,0,stream>>>(pconv, out, psum, psq, pg, pb);
}